// Round 1
// baseline (323.266 us; speedup 1.0000x reference)
//
#include <hip/hip_runtime.h>

#define Bsz 16
#define Tsz 4096
#define Dsz 512
#define Ksz 256
#define Msz (Bsz * Tsz)      // 65536
#define CHUNK 64
#define NCH (Tsz / CHUNK)    // 64

// ---------------- threefry2x32 (key = (0, 42)) — matches JAX exactly -------
__device__ __forceinline__ unsigned int rotl32(unsigned int x, int d) {
  return (x << d) | (x >> (32 - d));
}

__device__ void threefry_pair(unsigned int c0, unsigned int c1,
                              unsigned int& o0, unsigned int& o1) {
  const unsigned int k0 = 0u, k1 = 42u;
  const unsigned int k2 = k0 ^ k1 ^ 0x1BD11BDAu;
  unsigned int x0 = c0 + k0;
  unsigned int x1 = c1 + k1;
#define TF_ROUND(r) { x0 += x1; x1 = rotl32(x1, (r)); x1 ^= x0; }
  TF_ROUND(13) TF_ROUND(15) TF_ROUND(26) TF_ROUND(6)
  x0 += k1; x1 += k2 + 1u;
  TF_ROUND(17) TF_ROUND(29) TF_ROUND(16) TF_ROUND(24)
  x0 += k2; x1 += k0 + 2u;
  TF_ROUND(13) TF_ROUND(15) TF_ROUND(26) TF_ROUND(6)
  x0 += k0; x1 += k1 + 3u;
  TF_ROUND(17) TF_ROUND(29) TF_ROUND(16) TF_ROUND(24)
  x0 += k1; x1 += k2 + 4u;
  TF_ROUND(13) TF_ROUND(15) TF_ROUND(26) TF_ROUND(6)
  x0 += k2; x1 += k0 + 5u;
#undef TF_ROUND
  o0 = x0; o1 = x1;
}

// XLA ErfInv32 polynomial (math.cc)
__device__ float erfinv32(float x) {
  float w = -log1pf(-x * x);
  float p;
  if (w < 5.f) {
    w -= 2.5f;
    p = 2.81022636e-08f;
    p = fmaf(p, w, 3.43273939e-07f);
    p = fmaf(p, w, -3.5233877e-06f);
    p = fmaf(p, w, -4.39150654e-06f);
    p = fmaf(p, w, 0.00021858087f);
    p = fmaf(p, w, -0.00125372503f);
    p = fmaf(p, w, -0.00417768164f);
    p = fmaf(p, w, 0.246640727f);
    p = fmaf(p, w, 1.50140941f);
  } else {
    w = sqrtf(w) - 3.f;
    p = -0.000200214257f;
    p = fmaf(p, w, 0.000100950558f);
    p = fmaf(p, w, 0.00134934322f);
    p = fmaf(p, w, -0.00367342844f);
    p = fmaf(p, w, 0.00573950773f);
    p = fmaf(p, w, -0.0076224613f);
    p = fmaf(p, w, 0.00943887047f);
    p = fmaf(p, w, 1.00167406f);
    p = fmaf(p, w, 2.83297682f);
  }
  return p * x;
}

// JAX: bits -> uniform[-0.99999994, 1) -> sqrt(2)*erfinv
__device__ float bits_to_normal(unsigned int bits) {
  unsigned int fb = (bits >> 9) | 0x3f800000u;
  float f = __uint_as_float(fb) - 1.0f;   // [0,1)
  const float lo = -0.99999994f;          // nextafter(-1, 0) in f32
  float u = f * 2.0f + lo;                // hi - lo rounds to exactly 2.0f
  u = fmaxf(lo, u);
  return 1.41421356f * erfinv32(u);
}

__device__ float block_sum_512(float v, float* s_red) {
  #pragma unroll
  for (int o = 32; o > 0; o >>= 1) v += __shfl_down(v, o);
  const int lane = threadIdx.x & 63, wid = threadIdx.x >> 6;
  if (lane == 0) s_red[wid] = v;
  __syncthreads();
  float r = 0.f;
  #pragma unroll
  for (int i = 0; i < 8; ++i) r += s_red[i];
  __syncthreads();
  return r;
}

// --------- prep: u0 -> power iteration -> sigma; W/sigma; per-k constants --
__global__ __launch_bounds__(512) void prep_kernel(
    const float* __restrict__ s_real_raw, const float* __restrict__ s_imag,
    const float* __restrict__ tau_raw, const float* __restrict__ W,
    float* __restrict__ Wsc, float* __restrict__ consts) {
  __shared__ float s_u0[Ksz];
  __shared__ float s_v[Dsz];
  __shared__ float s_wv[Ksz];
  __shared__ float s_red[8];
  const int tid = threadIdx.x;
  const int lane = tid & 63, wid = tid >> 6;

  // u0 = jax.random.normal(key(42), (256,)): counts split as (i, i+128)
  if (tid < 128) {
    unsigned int y0, y1;
    threefry_pair((unsigned int)tid, (unsigned int)(tid + 128), y0, y1);
    s_u0[tid] = bits_to_normal(y0);
    s_u0[tid + 128] = bits_to_normal(y1);
  }
  __syncthreads();

  // normalize u0
  float val = (tid < Ksz) ? s_u0[tid] * s_u0[tid] : 0.f;
  float ss = block_sum_512(val, s_red);
  float inv = 1.f / fmaxf(sqrtf(ss), 1e-7f);
  if (tid < Ksz) s_u0[tid] *= inv;
  __syncthreads();

  // v = W^T u0 (each thread one d; coalesced over d)
  {
    float acc = 0.f;
    const int d = tid;
    #pragma unroll 4
    for (int k = 0; k < Ksz; ++k)
      acc = fmaf(W[(size_t)k * Dsz + d], s_u0[k], acc);
    s_v[d] = acc;
  }
  __syncthreads();
  float ssv = block_sum_512(s_v[tid] * s_v[tid], s_red);
  float invv = 1.f / fmaxf(sqrtf(ssv), 1e-7f);
  s_v[tid] *= invv;
  __syncthreads();

  // wv = W v : one wave per row, coalesced within wave
  for (int k = wid; k < Ksz; k += 8) {
    const float* wr = W + (size_t)k * Dsz;
    float p = 0.f;
    #pragma unroll
    for (int j = lane; j < Dsz; j += 64) p = fmaf(wr[j], s_v[j], p);
    #pragma unroll
    for (int o = 32; o > 0; o >>= 1) p += __shfl_down(p, o);
    if (lane == 0) s_wv[k] = p;
  }
  __syncthreads();
  float v2 = (tid < Ksz) ? s_wv[tid] * s_wv[tid] : 0.f;
  float sswv = block_sum_512(v2, s_red);
  // sigma = u.(Wv) with u = Wv/max(|Wv|,eps)  ->  |Wv|^2 / max(|Wv|, eps)
  float sigma = sswv / fmaxf(sqrtf(sswv), 1e-7f);
  float inv_sigma = 1.f / sigma;

  // W_sn = W / sigma
  for (int idx = tid; idx < Ksz * Dsz; idx += 512)
    Wsc[idx] = W[idx] * inv_sigma;

  // per-k recurrence constants: a = rho*e^{i theta}, A = a^64 (closed form)
  if (tid < Ksz) {
    float tr = tau_raw[0];
    float tau = fmaxf(tr, 0.f) + log1pf(expf(-fabsf(tr))) + 1e-3f;
    float srr = s_real_raw[tid];
    float sp = fmaxf(srr, 0.f) + log1pf(expf(-fabsf(srr)));
    float alpha0 = (sp + 1e-6f) * tau;
    float omega0 = s_imag[tid] * tau;
    const float dt = 1.f / 4095.f;
    float rho = expf(-alpha0 * dt);
    float ang = omega0 * dt;
    float ar = rho * cosf(ang);
    float ai = rho * sinf(ang);
    float rho64 = expf(-alpha0 * dt * 64.f);
    float ang64 = ang * 64.f;   // exact (x2^6)
    consts[tid] = ar;
    consts[Ksz + tid] = ai;
    consts[2 * Ksz + tid] = rho64 * cosf(ang64);
    consts[3 * Ksz + tid] = rho64 * sinf(ang64);
  }
}

// --------- GEMM f32: U[M,256] = X[M,512] * Wsc^T + b ----------------------
__global__ __launch_bounds__(256) void gemm_f32(
    const float* __restrict__ X, const float* __restrict__ Wsc,
    const float* __restrict__ bias, float* __restrict__ U) {
  __shared__ float Xs[16][132];   // [kk][m], pad -> bank rotation
  __shared__ float Ws[16][132];   // [kk][n]
  const int tid = threadIdx.x;
  const int tx = tid & 15;        // n micro (8 cols)
  const int ty = tid >> 4;        // m micro (8 rows)
  const size_t m0 = (size_t)blockIdx.y * 128;
  const int n0 = blockIdx.x * 128;
  const int lr = tid >> 2;          // 0..63
  const int lc = (tid & 3) << 2;    // 0,4,8,12

  const float* xg  = X + (m0 + lr) * Dsz + lc;
  const float* xg2 = xg + (size_t)64 * Dsz;
  const float* wg  = Wsc + (size_t)(n0 + lr) * Dsz + lc;
  const float* wg2 = wg + (size_t)64 * Dsz;

  float acc[8][8];
  #pragma unroll
  for (int i = 0; i < 8; ++i)
    #pragma unroll
    for (int j = 0; j < 8; ++j) acc[i][j] = 0.f;

  for (int kb = 0; kb < Dsz; kb += 16) {
    float4 xa = *(const float4*)(xg + kb);
    float4 xb = *(const float4*)(xg2 + kb);
    float4 wa = *(const float4*)(wg + kb);
    float4 wb = *(const float4*)(wg2 + kb);
    __syncthreads();
    Xs[lc + 0][lr] = xa.x; Xs[lc + 1][lr] = xa.y;
    Xs[lc + 2][lr] = xa.z; Xs[lc + 3][lr] = xa.w;
    Xs[lc + 0][lr + 64] = xb.x; Xs[lc + 1][lr + 64] = xb.y;
    Xs[lc + 2][lr + 64] = xb.z; Xs[lc + 3][lr + 64] = xb.w;
    Ws[lc + 0][lr] = wa.x; Ws[lc + 1][lr] = wa.y;
    Ws[lc + 2][lr] = wa.z; Ws[lc + 3][lr] = wa.w;
    Ws[lc + 0][lr + 64] = wb.x; Ws[lc + 1][lr + 64] = wb.y;
    Ws[lc + 2][lr + 64] = wb.z; Ws[lc + 3][lr + 64] = wb.w;
    __syncthreads();
    #pragma unroll
    for (int kk = 0; kk < 16; ++kk) {
      float a[8], bb[8];
      *(float4*)&a[0]  = *(const float4*)&Xs[kk][ty * 8];
      *(float4*)&a[4]  = *(const float4*)&Xs[kk][ty * 8 + 4];
      *(float4*)&bb[0] = *(const float4*)&Ws[kk][tx * 8];
      *(float4*)&bb[4] = *(const float4*)&Ws[kk][tx * 8 + 4];
      #pragma unroll
      for (int i = 0; i < 8; ++i)
        #pragma unroll
        for (int j = 0; j < 8; ++j)
          acc[i][j] = fmaf(a[i], bb[j], acc[i][j]);
    }
  }

  float bv[8];
  *(float4*)&bv[0] = *(const float4*)&bias[n0 + tx * 8];
  *(float4*)&bv[4] = *(const float4*)&bias[n0 + tx * 8 + 4];
  #pragma unroll
  for (int i = 0; i < 8; ++i) {
    size_t row = m0 + ty * 8 + i;
    float4 o0 = make_float4(acc[i][0] + bv[0], acc[i][1] + bv[1],
                            acc[i][2] + bv[2], acc[i][3] + bv[3]);
    float4 o1 = make_float4(acc[i][4] + bv[4], acc[i][5] + bv[5],
                            acc[i][6] + bv[6], acc[i][7] + bv[7]);
    *(float4*)&U[row * Ksz + n0 + tx * 8] = o0;
    *(float4*)&U[row * Ksz + n0 + tx * 8 + 4] = o1;
  }
}

// --------- scan pass 1: per-chunk local carry from zero --------------------
__global__ __launch_bounds__(256) void scan_summary(
    const float* __restrict__ U, const float* __restrict__ consts,
    float* __restrict__ carry) {
  const int k = threadIdx.x;
  const int bm = blockIdx.x;   // b*NCH + m
  const float ar = consts[k], ai = consts[Ksz + k];
  const float* up = U + (size_t)bm * (CHUNK * Ksz) + k;
  float c = 0.f, s = 0.f;
  #pragma unroll 8
  for (int t = 0; t < CHUNK; ++t) {
    float u = up[(size_t)t * Ksz];
    float cn = fmaf(ar, c, fmaf(-ai, s, u));
    s = fmaf(ai, c, ar * s);
    c = cn;
  }
  ((float2*)carry)[(size_t)bm * Ksz + k] = make_float2(c, s);
}

// --------- scan pass 2: exclusive prefix over chunks (A = a^64) ------------
__global__ __launch_bounds__(64) void scan_prefix(
    const float* __restrict__ consts, const float* __restrict__ carry,
    float* __restrict__ prefix) {
  const int k = blockIdx.y * 64 + threadIdx.x;
  const int b = blockIdx.x;
  const float Ar = consts[2 * Ksz + k], Ai = consts[3 * Ksz + k];
  const float2* cp = (const float2*)carry;
  float2* pp = (float2*)prefix;
  float c = 0.f, s = 0.f;
  for (int m = 0; m < NCH; ++m) {
    const size_t idx = (size_t)(b * NCH + m) * Ksz + k;
    pp[idx] = make_float2(c, s);
    float2 L = cp[idx];
    float cn = fmaf(Ar, c, fmaf(-Ai, s, L.x));
    float sn = fmaf(Ai, c, fmaf(Ar, s, L.y));
    c = cn; s = sn;
  }
}

// --------- scan pass 3: rescan chunk from true carry, write output ---------
__global__ __launch_bounds__(256) void scan_final(
    const float* __restrict__ U, const float* __restrict__ consts,
    const float* __restrict__ prefix, float* __restrict__ out) {
  const int k = threadIdx.x;
  const int bm = blockIdx.x;
  const float ar = consts[k], ai = consts[Ksz + k];
  float2 w = ((const float2*)prefix)[(size_t)bm * Ksz + k];
  float c = w.x, s = w.y;
  const float* up = U + (size_t)bm * (CHUNK * Ksz) + k;
  float* op = out + (size_t)bm * (CHUNK * 2 * Ksz);
  #pragma unroll 4
  for (int t = 0; t < CHUNK; ++t) {
    float u = up[(size_t)t * Ksz];
    float cn = fmaf(ar, c, fmaf(-ai, s, u));
    s = fmaf(ai, c, ar * s);
    c = cn;
    op[(size_t)t * 2 * Ksz + k] = c;
    op[(size_t)t * 2 * Ksz + Ksz + k] = s;
  }
}

extern "C" void kernel_launch(void* const* d_in, const int* in_sizes, int n_in,
                              void* d_out, int out_size, void* d_ws, size_t ws_size,
                              hipStream_t stream) {
  const float* x    = (const float*)d_in[0];
  const float* srr  = (const float*)d_in[1];
  const float* sim  = (const float*)d_in[2];
  const float* traw = (const float*)d_in[3];
  const float* W    = (const float*)d_in[4];
  const float* bias = (const float*)d_in[5];
  float* out = (float*)d_out;

  // ws layout (floats): Wsc[256*512] | consts[4*256] | U[65536*256]
  //                     | carry[16*64*256*2] | prefix[same]   ~= 71.8 MB
  float* wsf    = (float*)d_ws;
  float* Wsc    = wsf;
  float* consts = wsf + (size_t)Ksz * Dsz;                  // +131072
  float* U      = consts + 4 * Ksz;                         // +1024
  float* carry  = U + (size_t)Msz * Ksz;                    // +16777216
  float* prefix = carry + (size_t)2 * Bsz * NCH * Ksz;      // +524288

  prep_kernel<<<1, 512, 0, stream>>>(srr, sim, traw, W, Wsc, consts);
  gemm_f32<<<dim3(Ksz / 128, Msz / 128), 256, 0, stream>>>(x, Wsc, bias, U);
  scan_summary<<<Bsz * NCH, Ksz, 0, stream>>>(U, consts, carry);
  scan_prefix<<<dim3(Bsz, Ksz / 64), 64, 0, stream>>>(consts, carry, prefix);
  scan_final<<<Bsz * NCH, Ksz, 0, stream>>>(U, consts, prefix, out);
}

// Round 2
// 190.898 us; speedup vs baseline: 1.6934x; 1.6934x over previous
//
#include <hip/hip_runtime.h>

#define Bsz 16
#define Tsz 4096
#define Dsz 512
#define Ksz 256
#define Msz (Bsz * Tsz)      // 65536
#define CHUNK 64
#define NCH (Tsz / CHUNK)    // 64

typedef __attribute__((ext_vector_type(8))) short short8;
typedef __attribute__((ext_vector_type(4))) float f32x4;

// ---------------- threefry2x32 (key = (0, 42)) — matches JAX exactly -------
__device__ __forceinline__ unsigned int rotl32(unsigned int x, int d) {
  return (x << d) | (x >> (32 - d));
}

__device__ void threefry_pair(unsigned int c0, unsigned int c1,
                              unsigned int& o0, unsigned int& o1) {
  const unsigned int k0 = 0u, k1 = 42u;
  const unsigned int k2 = k0 ^ k1 ^ 0x1BD11BDAu;
  unsigned int x0 = c0 + k0;
  unsigned int x1 = c1 + k1;
#define TF_ROUND(r) { x0 += x1; x1 = rotl32(x1, (r)); x1 ^= x0; }
  TF_ROUND(13) TF_ROUND(15) TF_ROUND(26) TF_ROUND(6)
  x0 += k1; x1 += k2 + 1u;
  TF_ROUND(17) TF_ROUND(29) TF_ROUND(16) TF_ROUND(24)
  x0 += k2; x1 += k0 + 2u;
  TF_ROUND(13) TF_ROUND(15) TF_ROUND(26) TF_ROUND(6)
  x0 += k0; x1 += k1 + 3u;
  TF_ROUND(17) TF_ROUND(29) TF_ROUND(16) TF_ROUND(24)
  x0 += k1; x1 += k2 + 4u;
  TF_ROUND(13) TF_ROUND(15) TF_ROUND(26) TF_ROUND(6)
  x0 += k2; x1 += k0 + 5u;
#undef TF_ROUND
  o0 = x0; o1 = x1;
}

// XLA ErfInv32 polynomial (math.cc)
__device__ float erfinv32(float x) {
  float w = -log1pf(-x * x);
  float p;
  if (w < 5.f) {
    w -= 2.5f;
    p = 2.81022636e-08f;
    p = fmaf(p, w, 3.43273939e-07f);
    p = fmaf(p, w, -3.5233877e-06f);
    p = fmaf(p, w, -4.39150654e-06f);
    p = fmaf(p, w, 0.00021858087f);
    p = fmaf(p, w, -0.00125372503f);
    p = fmaf(p, w, -0.00417768164f);
    p = fmaf(p, w, 0.246640727f);
    p = fmaf(p, w, 1.50140941f);
  } else {
    w = sqrtf(w) - 3.f;
    p = -0.000200214257f;
    p = fmaf(p, w, 0.000100950558f);
    p = fmaf(p, w, 0.00134934322f);
    p = fmaf(p, w, -0.00367342844f);
    p = fmaf(p, w, 0.00573950773f);
    p = fmaf(p, w, -0.0076224613f);
    p = fmaf(p, w, 0.00943887047f);
    p = fmaf(p, w, 1.00167406f);
    p = fmaf(p, w, 2.83297682f);
  }
  return p * x;
}

// JAX: bits -> uniform[-0.99999994, 1) -> sqrt(2)*erfinv
__device__ float bits_to_normal(unsigned int bits) {
  unsigned int fb = (bits >> 9) | 0x3f800000u;
  float f = __uint_as_float(fb) - 1.0f;   // [0,1)
  const float lo = -0.99999994f;          // nextafter(-1, 0) in f32
  float u = f * 2.0f + lo;                // hi - lo rounds to exactly 2.0f
  u = fmaxf(lo, u);
  return 1.41421356f * erfinv32(u);
}

__device__ float block_sum_512(float v, float* s_red) {
  #pragma unroll
  for (int o = 32; o > 0; o >>= 1) v += __shfl_down(v, o);
  const int lane = threadIdx.x & 63, wid = threadIdx.x >> 6;
  if (lane == 0) s_red[wid] = v;
  __syncthreads();
  float r = 0.f;
  #pragma unroll
  for (int i = 0; i < 8; ++i) r += s_red[i];
  __syncthreads();
  return r;
}

// --------- prep: u0 -> power iteration -> sigma; W/sigma; per-k constants --
__global__ __launch_bounds__(512) void prep_kernel(
    const float* __restrict__ s_real_raw, const float* __restrict__ s_imag,
    const float* __restrict__ tau_raw, const float* __restrict__ W,
    float* __restrict__ Wsc, float* __restrict__ consts) {
  __shared__ float s_u0[Ksz];
  __shared__ float s_v[Dsz];
  __shared__ float s_wv[Ksz];
  __shared__ float s_red[8];
  const int tid = threadIdx.x;
  const int lane = tid & 63, wid = tid >> 6;

  // u0 = jax.random.normal(key(42), (256,)): counts split as (i, i+128)
  if (tid < 128) {
    unsigned int y0, y1;
    threefry_pair((unsigned int)tid, (unsigned int)(tid + 128), y0, y1);
    s_u0[tid] = bits_to_normal(y0);
    s_u0[tid + 128] = bits_to_normal(y1);
  }
  __syncthreads();

  // normalize u0
  float val = (tid < Ksz) ? s_u0[tid] * s_u0[tid] : 0.f;
  float ss = block_sum_512(val, s_red);
  float inv = 1.f / fmaxf(sqrtf(ss), 1e-7f);
  if (tid < Ksz) s_u0[tid] *= inv;
  __syncthreads();

  // v = W^T u0 (each thread one d; coalesced over d)
  {
    float acc = 0.f;
    const int d = tid;
    #pragma unroll 4
    for (int k = 0; k < Ksz; ++k)
      acc = fmaf(W[(size_t)k * Dsz + d], s_u0[k], acc);
    s_v[d] = acc;
  }
  __syncthreads();
  float ssv = block_sum_512(s_v[tid] * s_v[tid], s_red);
  float invv = 1.f / fmaxf(sqrtf(ssv), 1e-7f);
  s_v[tid] *= invv;
  __syncthreads();

  // wv = W v : one wave per row, coalesced within wave
  for (int k = wid; k < Ksz; k += 8) {
    const float* wr = W + (size_t)k * Dsz;
    float p = 0.f;
    #pragma unroll
    for (int j = lane; j < Dsz; j += 64) p = fmaf(wr[j], s_v[j], p);
    #pragma unroll
    for (int o = 32; o > 0; o >>= 1) p += __shfl_down(p, o);
    if (lane == 0) s_wv[k] = p;
  }
  __syncthreads();
  float v2 = (tid < Ksz) ? s_wv[tid] * s_wv[tid] : 0.f;
  float sswv = block_sum_512(v2, s_red);
  // sigma = u.(Wv) with u = Wv/max(|Wv|,eps)  ->  |Wv|^2 / max(|Wv|, eps)
  float sigma = sswv / fmaxf(sqrtf(sswv), 1e-7f);
  float inv_sigma = 1.f / sigma;

  // W_sn = W / sigma
  for (int idx = tid; idx < Ksz * Dsz; idx += 512)
    Wsc[idx] = W[idx] * inv_sigma;

  // per-k recurrence constants: a = rho*e^{i theta}, A = a^64 (closed form)
  if (tid < Ksz) {
    float tr = tau_raw[0];
    float tau = fmaxf(tr, 0.f) + log1pf(expf(-fabsf(tr))) + 1e-3f;
    float srr = s_real_raw[tid];
    float sp = fmaxf(srr, 0.f) + log1pf(expf(-fabsf(srr)));
    float alpha0 = (sp + 1e-6f) * tau;
    float omega0 = s_imag[tid] * tau;
    const float dt = 1.f / 4095.f;
    float rho = expf(-alpha0 * dt);
    float ang = omega0 * dt;
    float ar = rho * cosf(ang);
    float ai = rho * sinf(ang);
    float rho64 = expf(-alpha0 * dt * 64.f);
    float ang64 = ang * 64.f;   // exact (x2^6)
    consts[tid] = ar;
    consts[Ksz + tid] = ai;
    consts[2 * Ksz + tid] = rho64 * cosf(ang64);
    consts[3 * Ksz + tid] = rho64 * sinf(ang64);
  }
}

// --------- MFMA GEMM (3-term bf16 split): U[M,256] = X[M,512]*Wsc^T + b ----
// BM=128, BN=256(all), BK=32, 512 threads = 8 waves (2m x 4n), frag 4x4.
// LDS rows: [64B h | 64B l] = 128B, XOR-swizzle ((r&7)<<4) -> conflict-free.
__device__ __forceinline__ unsigned int bf16rne(float f) {
  unsigned int u = __float_as_uint(f);
  return (u + 0x7FFFu + ((u >> 16) & 1u)) >> 16;
}

__global__ __launch_bounds__(512, 2) void gemm_mfma(
    const float* __restrict__ X, const float* __restrict__ Wsc,
    const float* __restrict__ bias, float* __restrict__ U) {
  __shared__ unsigned int lds[(16384 + 32768) / 4];   // A 16KB, B 32KB
  char* const Abase = (char*)lds;
  char* const Bbase = (char*)lds + 16384;

  const int tid = threadIdx.x;
  const size_t m0 = (size_t)blockIdx.x * 128;

  // staging mapping: thread -> (row r = tid>>2, k-chunk c = tid&3 of 8 floats)
  const int sr = tid >> 2;              // 0..127
  const int sc = (tid & 3) * 8;         // float k-offset 0,8,16,24
  const float* gx = X + (m0 + sr) * Dsz + sc;
  const float* gw = Wsc + (size_t)sr * Dsz + sc;       // rows sr and sr+128

  float xa[8], wa[8], wb[8];

  const int swz = (sr & 7) << 4;
  unsigned int* const awr_h = (unsigned int*)(Abase + sr * 128 + ((sc * 2) ^ swz));
  unsigned int* const awr_l = (unsigned int*)(Abase + sr * 128 + ((64 + sc * 2) ^ swz));
  unsigned int* const bwr_h  = (unsigned int*)(Bbase + sr * 128 + ((sc * 2) ^ swz));
  unsigned int* const bwr_l  = (unsigned int*)(Bbase + sr * 128 + ((64 + sc * 2) ^ swz));
  const int sr2 = sr + 128;
  const int swz2 = (sr2 & 7) << 4;      // == swz
  unsigned int* const bwr2_h = (unsigned int*)(Bbase + sr2 * 128 + ((sc * 2) ^ swz2));
  unsigned int* const bwr2_l = (unsigned int*)(Bbase + sr2 * 128 + ((64 + sc * 2) ^ swz2));

  // wave/frag decomposition
  const int lane = tid & 63;
  const int wid = tid >> 6;
  const int wm = wid >> 2;              // 0..1 -> m offset wm*64
  const int wn = wid & 3;               // 0..3 -> n offset wn*64
  const int lr = lane & 15;
  const int lg = lane >> 4;             // k-group

  f32x4 acc[4][4];
  #pragma unroll
  for (int i = 0; i < 4; ++i)
    #pragma unroll
    for (int j = 0; j < 4; ++j) acc[i][j] = (f32x4)(0.f);

  #define LOAD_TILE(kb)  do {                                   \
    const float* p = gx + (kb) * 32;                            \
    *(float4*)&xa[0] = *(const float4*)p;                       \
    *(float4*)&xa[4] = *(const float4*)(p + 4);                 \
    const float* q = gw + (kb) * 32;                            \
    *(float4*)&wa[0] = *(const float4*)q;                       \
    *(float4*)&wa[4] = *(const float4*)(q + 4);                 \
    const float* q2 = q + (size_t)128 * Dsz;                    \
    *(float4*)&wb[0] = *(const float4*)q2;                      \
    *(float4*)&wb[4] = *(const float4*)(q2 + 4);                \
  } while (0)

  #define SPLIT_STORE(v, dsth, dstl) do {                       \
    unsigned int hh[4], ll[4];                                  \
    _Pragma("unroll")                                           \
    for (int i = 0; i < 4; ++i) {                               \
      float v0 = (v)[2 * i], v1 = (v)[2 * i + 1];               \
      unsigned int u0 = __float_as_uint(v0);                    \
      unsigned int u1 = __float_as_uint(v1);                    \
      hh[i] = (u0 >> 16) | (u1 & 0xFFFF0000u);                  \
      float r0 = v0 - __uint_as_float(u0 & 0xFFFF0000u);        \
      float r1 = v1 - __uint_as_float(u1 & 0xFFFF0000u);        \
      ll[i] = bf16rne(r0) | (bf16rne(r1) << 16);                \
    }                                                           \
    *(int4*)(dsth) = *(int4*)hh;                                \
    *(int4*)(dstl) = *(int4*)ll;                                \
  } while (0)

  LOAD_TILE(0);

  for (int kb = 0; kb < 16; ++kb) {
    if (kb) __syncthreads();            // previous tile's compute done
    SPLIT_STORE(xa, awr_h, awr_l);
    SPLIT_STORE(wa, bwr_h, bwr_l);
    SPLIT_STORE(wb, bwr2_h, bwr2_l);
    if (kb < 15) LOAD_TILE(kb + 1);     // prefetch overlaps compute
    __syncthreads();

    short8 ah[4], al[4], bh[4], bl[4];
    #pragma unroll
    for (int f = 0; f < 4; ++f) {
      int r = wm * 64 + f * 16 + lr;
      int sz = (r & 7) << 4;
      ah[f] = *(const short8*)(Abase + r * 128 + ((lg * 16) ^ sz));
      al[f] = *(const short8*)(Abase + r * 128 + ((64 + lg * 16) ^ sz));
      int rb = wn * 64 + f * 16 + lr;
      int szb = (rb & 7) << 4;
      bh[f] = *(const short8*)(Bbase + rb * 128 + ((lg * 16) ^ szb));
      bl[f] = *(const short8*)(Bbase + rb * 128 + ((64 + lg * 16) ^ szb));
    }
    #pragma unroll
    for (int mf = 0; mf < 4; ++mf)
      #pragma unroll
      for (int nf = 0; nf < 4; ++nf) {
        acc[mf][nf] = __builtin_amdgcn_mfma_f32_16x16x32_bf16(
            ah[mf], bh[nf], acc[mf][nf], 0, 0, 0);
        acc[mf][nf] = __builtin_amdgcn_mfma_f32_16x16x32_bf16(
            ah[mf], bl[nf], acc[mf][nf], 0, 0, 0);
        acc[mf][nf] = __builtin_amdgcn_mfma_f32_16x16x32_bf16(
            al[mf], bh[nf], acc[mf][nf], 0, 0, 0);
      }
  }

  // epilogue: bias + store (C/D: col = lane&15, row = (lane>>4)*4 + reg)
  #pragma unroll
  for (int nf = 0; nf < 4; ++nf) {
    const int n = wn * 64 + nf * 16 + lr;
    const float bv = bias[n];
    #pragma unroll
    for (int mf = 0; mf < 4; ++mf) {
      #pragma unroll
      for (int j = 0; j < 4; ++j) {
        size_t m = m0 + wm * 64 + mf * 16 + lg * 4 + j;
        U[m * Ksz + n] = acc[mf][nf][j] + bv;
      }
    }
  }
  #undef LOAD_TILE
  #undef SPLIT_STORE
}

// --------- scan pass 1: per-chunk local carry from zero --------------------
__global__ __launch_bounds__(256) void scan_summary(
    const float* __restrict__ U, const float* __restrict__ consts,
    float* __restrict__ carry) {
  const int k = threadIdx.x;
  const int bm = blockIdx.x;   // b*NCH + m
  const float ar = consts[k], ai = consts[Ksz + k];
  const float* up = U + (size_t)bm * (CHUNK * Ksz) + k;
  float c = 0.f, s = 0.f;
  #pragma unroll 8
  for (int t = 0; t < CHUNK; ++t) {
    float u = up[(size_t)t * Ksz];
    float cn = fmaf(ar, c, fmaf(-ai, s, u));
    s = fmaf(ai, c, ar * s);
    c = cn;
  }
  ((float2*)carry)[(size_t)bm * Ksz + k] = make_float2(c, s);
}

// --------- scan pass 2: exclusive prefix over chunks (A = a^64) ------------
__global__ __launch_bounds__(64) void scan_prefix(
    const float* __restrict__ consts, const float* __restrict__ carry,
    float* __restrict__ prefix) {
  const int k = blockIdx.y * 64 + threadIdx.x;
  const int b = blockIdx.x;
  const float Ar = consts[2 * Ksz + k], Ai = consts[3 * Ksz + k];
  const float2* cp = (const float2*)carry;
  float2* pp = (float2*)prefix;
  float c = 0.f, s = 0.f;
  for (int m = 0; m < NCH; ++m) {
    const size_t idx = (size_t)(b * NCH + m) * Ksz + k;
    pp[idx] = make_float2(c, s);
    float2 L = cp[idx];
    float cn = fmaf(Ar, c, fmaf(-Ai, s, L.x));
    float sn = fmaf(Ai, c, fmaf(Ar, s, L.y));
    c = cn; s = sn;
  }
}

// --------- scan pass 3: rescan chunk from true carry, write output ---------
__global__ __launch_bounds__(256) void scan_final(
    const float* __restrict__ U, const float* __restrict__ consts,
    const float* __restrict__ prefix, float* __restrict__ out) {
  const int k = threadIdx.x;
  const int bm = blockIdx.x;
  const float ar = consts[k], ai = consts[Ksz + k];
  float2 w = ((const float2*)prefix)[(size_t)bm * Ksz + k];
  float c = w.x, s = w.y;
  const float* up = U + (size_t)bm * (CHUNK * Ksz) + k;
  float* op = out + (size_t)bm * (CHUNK * 2 * Ksz);
  #pragma unroll 4
  for (int t = 0; t < CHUNK; ++t) {
    float u = up[(size_t)t * Ksz];
    float cn = fmaf(ar, c, fmaf(-ai, s, u));
    s = fmaf(ai, c, ar * s);
    c = cn;
    op[(size_t)t * 2 * Ksz + k] = c;
    op[(size_t)t * 2 * Ksz + Ksz + k] = s;
  }
}

extern "C" void kernel_launch(void* const* d_in, const int* in_sizes, int n_in,
                              void* d_out, int out_size, void* d_ws, size_t ws_size,
                              hipStream_t stream) {
  const float* x    = (const float*)d_in[0];
  const float* srr  = (const float*)d_in[1];
  const float* sim  = (const float*)d_in[2];
  const float* traw = (const float*)d_in[3];
  const float* W    = (const float*)d_in[4];
  const float* bias = (const float*)d_in[5];
  float* out = (float*)d_out;

  // ws layout (floats): Wsc[256*512] | consts[4*256] | U[65536*256]
  //                     | carry[16*64*256*2] | prefix[same]   ~= 71.8 MB
  float* wsf    = (float*)d_ws;
  float* Wsc    = wsf;
  float* consts = wsf + (size_t)Ksz * Dsz;                  // +131072
  float* U      = consts + 4 * Ksz;                         // +1024
  float* carry  = U + (size_t)Msz * Ksz;                    // +16777216
  float* prefix = carry + (size_t)2 * Bsz * NCH * Ksz;      // +524288

  prep_kernel<<<1, 512, 0, stream>>>(srr, sim, traw, W, Wsc, consts);
  gemm_mfma<<<Msz / 128, 512, 0, stream>>>(x, Wsc, bias, U);
  scan_summary<<<Bsz * NCH, Ksz, 0, stream>>>(U, consts, carry);
  scan_prefix<<<dim3(Bsz, Ksz / 64), 64, 0, stream>>>(consts, carry, prefix);
  scan_final<<<Bsz * NCH, Ksz, 0, stream>>>(U, consts, prefix, out);
}

// Round 3
// 167.752 us; speedup vs baseline: 1.9270x; 1.1380x over previous
//
#include <hip/hip_runtime.h>

#define Bsz 16
#define Tsz 4096
#define Dsz 512
#define Ksz 256
#define Msz (Bsz * Tsz)      // 65536
#define CHUNK 64
#define NCH (Tsz / CHUNK)    // 64

typedef __attribute__((ext_vector_type(8))) short short8;
typedef __attribute__((ext_vector_type(4))) float f32x4;

// ---------------- threefry2x32 (key = (0, 42)) — matches JAX exactly -------
__device__ __forceinline__ unsigned int rotl32(unsigned int x, int d) {
  return (x << d) | (x >> (32 - d));
}

__device__ void threefry_pair(unsigned int c0, unsigned int c1,
                              unsigned int& o0, unsigned int& o1) {
  const unsigned int k0 = 0u, k1 = 42u;
  const unsigned int k2 = k0 ^ k1 ^ 0x1BD11BDAu;
  unsigned int x0 = c0 + k0;
  unsigned int x1 = c1 + k1;
#define TF_ROUND(r) { x0 += x1; x1 = rotl32(x1, (r)); x1 ^= x0; }
  TF_ROUND(13) TF_ROUND(15) TF_ROUND(26) TF_ROUND(6)
  x0 += k1; x1 += k2 + 1u;
  TF_ROUND(17) TF_ROUND(29) TF_ROUND(16) TF_ROUND(24)
  x0 += k2; x1 += k0 + 2u;
  TF_ROUND(13) TF_ROUND(15) TF_ROUND(26) TF_ROUND(6)
  x0 += k0; x1 += k1 + 3u;
  TF_ROUND(17) TF_ROUND(29) TF_ROUND(16) TF_ROUND(24)
  x0 += k1; x1 += k2 + 4u;
  TF_ROUND(13) TF_ROUND(15) TF_ROUND(26) TF_ROUND(6)
  x0 += k2; x1 += k0 + 5u;
#undef TF_ROUND
  o0 = x0; o1 = x1;
}

// XLA ErfInv32 polynomial (math.cc)
__device__ float erfinv32(float x) {
  float w = -log1pf(-x * x);
  float p;
  if (w < 5.f) {
    w -= 2.5f;
    p = 2.81022636e-08f;
    p = fmaf(p, w, 3.43273939e-07f);
    p = fmaf(p, w, -3.5233877e-06f);
    p = fmaf(p, w, -4.39150654e-06f);
    p = fmaf(p, w, 0.00021858087f);
    p = fmaf(p, w, -0.00125372503f);
    p = fmaf(p, w, -0.00417768164f);
    p = fmaf(p, w, 0.246640727f);
    p = fmaf(p, w, 1.50140941f);
  } else {
    w = sqrtf(w) - 3.f;
    p = -0.000200214257f;
    p = fmaf(p, w, 0.000100950558f);
    p = fmaf(p, w, 0.00134934322f);
    p = fmaf(p, w, -0.00367342844f);
    p = fmaf(p, w, 0.00573950773f);
    p = fmaf(p, w, -0.0076224613f);
    p = fmaf(p, w, 0.00943887047f);
    p = fmaf(p, w, 1.00167406f);
    p = fmaf(p, w, 2.83297682f);
  }
  return p * x;
}

// JAX: bits -> uniform[-0.99999994, 1) -> sqrt(2)*erfinv
__device__ float bits_to_normal(unsigned int bits) {
  unsigned int fb = (bits >> 9) | 0x3f800000u;
  float f = __uint_as_float(fb) - 1.0f;   // [0,1)
  const float lo = -0.99999994f;          // nextafter(-1, 0) in f32
  float u = f * 2.0f + lo;                // hi - lo rounds to exactly 2.0f
  u = fmaxf(lo, u);
  return 1.41421356f * erfinv32(u);
}

__device__ float block_sum_512(float v, float* s_red) {
  #pragma unroll
  for (int o = 32; o > 0; o >>= 1) v += __shfl_down(v, o);
  const int lane = threadIdx.x & 63, wid = threadIdx.x >> 6;
  if (lane == 0) s_red[wid] = v;
  __syncthreads();
  float r = 0.f;
  #pragma unroll
  for (int i = 0; i < 8; ++i) r += s_red[i];
  __syncthreads();
  return r;
}

__device__ __forceinline__ unsigned int bf16rne(float f) {
  unsigned int u = __float_as_uint(f);
  return (u + 0x7FFFu + ((u >> 16) & 1u)) >> 16;
}

// --------- prep: u0 -> power iteration -> sigma + per-k recurrence consts --
__global__ __launch_bounds__(512) void prep_kernel(
    const float* __restrict__ s_real_raw, const float* __restrict__ s_imag,
    const float* __restrict__ tau_raw, const float* __restrict__ W,
    float* __restrict__ consts) {
  __shared__ float s_u0[Ksz];
  __shared__ float s_v[Dsz];
  __shared__ float s_wv[Ksz];
  __shared__ float s_red[8];
  const int tid = threadIdx.x;
  const int lane = tid & 63, wid = tid >> 6;

  // u0 = jax.random.normal(key(42), (256,)): counts split as (i, i+128)
  if (tid < 128) {
    unsigned int y0, y1;
    threefry_pair((unsigned int)tid, (unsigned int)(tid + 128), y0, y1);
    s_u0[tid] = bits_to_normal(y0);
    s_u0[tid + 128] = bits_to_normal(y1);
  }
  __syncthreads();

  // normalize u0
  float val = (tid < Ksz) ? s_u0[tid] * s_u0[tid] : 0.f;
  float ss = block_sum_512(val, s_red);
  float inv = 1.f / fmaxf(sqrtf(ss), 1e-7f);
  if (tid < Ksz) s_u0[tid] *= inv;
  __syncthreads();

  // v = W^T u0 (each thread one d; coalesced over d)
  {
    float acc = 0.f;
    const int d = tid;
    #pragma unroll 4
    for (int k = 0; k < Ksz; ++k)
      acc = fmaf(W[(size_t)k * Dsz + d], s_u0[k], acc);
    s_v[d] = acc;
  }
  __syncthreads();
  float ssv = block_sum_512(s_v[tid] * s_v[tid], s_red);
  float invv = 1.f / fmaxf(sqrtf(ssv), 1e-7f);
  s_v[tid] *= invv;
  __syncthreads();

  // wv = W v : one wave per row, coalesced within wave
  for (int k = wid; k < Ksz; k += 8) {
    const float* wr = W + (size_t)k * Dsz;
    float p = 0.f;
    #pragma unroll
    for (int j = lane; j < Dsz; j += 64) p = fmaf(wr[j], s_v[j], p);
    #pragma unroll
    for (int o = 32; o > 0; o >>= 1) p += __shfl_down(p, o);
    if (lane == 0) s_wv[k] = p;
  }
  __syncthreads();
  float v2 = (tid < Ksz) ? s_wv[tid] * s_wv[tid] : 0.f;
  float sswv = block_sum_512(v2, s_red);
  // sigma = u.(Wv) with u = Wv/max(|Wv|,eps)  ->  |Wv|^2 / max(|Wv|, eps)
  float sigma = sswv / fmaxf(sqrtf(sswv), 1e-7f);

  if (tid == 0) consts[4 * Ksz] = 1.f / sigma;

  // per-k recurrence constants: a = rho*e^{i theta}, A = a^64 (closed form)
  if (tid < Ksz) {
    float tr = tau_raw[0];
    float tau = fmaxf(tr, 0.f) + log1pf(expf(-fabsf(tr))) + 1e-3f;
    float srr = s_real_raw[tid];
    float sp = fmaxf(srr, 0.f) + log1pf(expf(-fabsf(srr)));
    float alpha0 = (sp + 1e-6f) * tau;
    float omega0 = s_imag[tid] * tau;
    const float dt = 1.f / 4095.f;
    float rho = expf(-alpha0 * dt);
    float ang = omega0 * dt;
    float ar = rho * cosf(ang);
    float ai = rho * sinf(ang);
    float rho64 = expf(-alpha0 * dt * 64.f);
    float ang64 = ang * 64.f;   // exact (x2^6)
    consts[tid] = ar;
    consts[Ksz + tid] = ai;
    consts[2 * Ksz + tid] = rho64 * cosf(ang64);
    consts[3 * Ksz + tid] = rho64 * sinf(ang64);
  }
}

// --------- wpack: W/sigma -> bf16 h/l in MFMA B-fragment order -------------
// Layout: [kb(16)][nb(16)] blobs of 1KB; byte addr = (kb*16+nb)*1024 + lane*16,
// lane = lg*16 + lr holds W[row nb*16+lr][kb*32 + lg*8 .. +8] as 8 bf16.
__global__ __launch_bounds__(64) void wpack_kernel(
    const float* __restrict__ W, const float* __restrict__ consts,
    unsigned int* __restrict__ WfH, unsigned int* __restrict__ WfL) {
  const int kb = blockIdx.x >> 4;
  const int nb = blockIdx.x & 15;
  const int lane = threadIdx.x;
  const int lr = lane & 15, lg = lane >> 4;
  const float inv_sigma = consts[4 * Ksz];
  const float* src = W + (size_t)(nb * 16 + lr) * Dsz + kb * 32 + lg * 8;
  float v[8];
  *(float4*)&v[0] = *(const float4*)src;
  *(float4*)&v[4] = *(const float4*)(src + 4);
  unsigned int hh[4], ll[4];
  #pragma unroll
  for (int i = 0; i < 4; ++i) {
    float v0 = v[2 * i] * inv_sigma, v1 = v[2 * i + 1] * inv_sigma;
    unsigned int u0 = __float_as_uint(v0);
    unsigned int u1 = __float_as_uint(v1);
    hh[i] = (u0 >> 16) | (u1 & 0xFFFF0000u);
    float r0 = v0 - __uint_as_float(u0 & 0xFFFF0000u);
    float r1 = v1 - __uint_as_float(u1 & 0xFFFF0000u);
    ll[i] = bf16rne(r0) | (bf16rne(r1) << 16);
  }
  const size_t off = (size_t)blockIdx.x * 256 + lane * 4;   // in uints
  *(int4*)(WfH + off) = *(int4*)hh;
  *(int4*)(WfL + off) = *(int4*)ll;
}

// --------- MFMA GEMM: U[M,256] = X[M,512]*(W/sigma)^T + b ------------------
// BM=64, BN=256, BK=32, 256 threads = 4 waves (wn 0..3), frag 4x4 per wave.
// A: f32->bf16 h/l split in-reg, double-buffered LDS (2x8KB), XOR-swizzled.
// B: bf16 frags loaded straight from pre-packed global (L2-resident).
// Raw s_barrier + lgkmcnt-only wait keeps global prefetches in flight.
__global__ __launch_bounds__(256, 3) void gemm_mfma(
    const float* __restrict__ X, const unsigned int* __restrict__ WfH,
    const unsigned int* __restrict__ WfL, const float* __restrict__ bias,
    float* __restrict__ U) {
  __shared__ unsigned int ldsA[2][2048];   // 2 x 8KB: 64 rows x [64B h|64B l]

  const int tid = threadIdx.x;
  const size_t m0 = (size_t)blockIdx.x * 64;

  // A staging: thread -> (row sr = tid>>2, k-chunk sc = (tid&3)*8 floats)
  const int sr = tid >> 2;              // 0..63
  const int sc = (tid & 3) * 8;
  const float* gx = X + (m0 + sr) * Dsz + sc;
  const int swz = (sr & 7) << 4;
  const int aoff_h = sr * 128 + ((sc * 2) ^ swz);
  const int aoff_l = sr * 128 + (((64 + sc * 2)) ^ swz);

  const int lane = tid & 63;
  const int wn = tid >> 6;              // wave -> n-offset wn*64
  const int lr = lane & 15;
  const int lg = lane >> 4;

  float xa[8];
  #define LOAD_A(kb) do {                                  \
    const float* p = gx + (kb) * 32;                       \
    *(float4*)&xa[0] = *(const float4*)p;                  \
    *(float4*)&xa[4] = *(const float4*)(p + 4);            \
  } while (0)

  LOAD_A(0);

  f32x4 acc[4][4];
  #pragma unroll
  for (int i = 0; i < 4; ++i)
    #pragma unroll
    for (int j = 0; j < 4; ++j) acc[i][j] = (f32x4)(0.f);

  const char* const wfh = (const char*)WfH + (size_t)wn * 4096 + lane * 16;
  const char* const wfl = (const char*)WfL + (size_t)wn * 4096 + lane * 16;

  for (int kb = 0; kb < 16; ++kb) {
    char* const Ab = (char*)ldsA[kb & 1];
    // split-convert A and store to LDS (h | l halves, swizzled)
    {
      unsigned int hh[4], llw[4];
      #pragma unroll
      for (int i = 0; i < 4; ++i) {
        float v0 = xa[2 * i], v1 = xa[2 * i + 1];
        unsigned int u0 = __float_as_uint(v0);
        unsigned int u1 = __float_as_uint(v1);
        hh[i] = (u0 >> 16) | (u1 & 0xFFFF0000u);
        float r0 = v0 - __uint_as_float(u0 & 0xFFFF0000u);
        float r1 = v1 - __uint_as_float(u1 & 0xFFFF0000u);
        llw[i] = bf16rne(r0) | (bf16rne(r1) << 16);
      }
      *(int4*)(Ab + aoff_h) = *(int4*)hh;
      *(int4*)(Ab + aoff_l) = *(int4*)llw;
    }

    // B fragments for THIS tile: straight from L2, no LDS
    short8 bh[4], bl[4];
    {
      const size_t tb = (size_t)kb * 16384;   // kb*16 blobs * 1KB
      #pragma unroll
      for (int f = 0; f < 4; ++f) {
        bh[f] = *(const short8*)(wfh + tb + (size_t)f * 1024);
        bl[f] = *(const short8*)(wfl + tb + (size_t)f * 1024);
      }
    }

    // prefetch next A tile (global, NOT drained by the barrier below)
    if (kb < 15) LOAD_A(kb + 1);

    asm volatile("s_waitcnt lgkmcnt(0)" ::: "memory");  // my ds_writes done
    __builtin_amdgcn_s_barrier();                       // all waves wrote buf
    __builtin_amdgcn_sched_barrier(0);

    short8 ah[4], al[4];
    #pragma unroll
    for (int f = 0; f < 4; ++f) {
      const int r = f * 16 + lr;
      const int sz = (r & 7) << 4;
      ah[f] = *(const short8*)(Ab + r * 128 + ((lg * 16) ^ sz));
      al[f] = *(const short8*)(Ab + r * 128 + ((64 + lg * 16) ^ sz));
    }
    #pragma unroll
    for (int mf = 0; mf < 4; ++mf)
      #pragma unroll
      for (int nf = 0; nf < 4; ++nf) {
        acc[mf][nf] = __builtin_amdgcn_mfma_f32_16x16x32_bf16(
            ah[mf], bh[nf], acc[mf][nf], 0, 0, 0);
        acc[mf][nf] = __builtin_amdgcn_mfma_f32_16x16x32_bf16(
            ah[mf], bl[nf], acc[mf][nf], 0, 0, 0);
        acc[mf][nf] = __builtin_amdgcn_mfma_f32_16x16x32_bf16(
            al[mf], bh[nf], acc[mf][nf], 0, 0, 0);
      }
  }
  #undef LOAD_A

  // epilogue: bias + store (C/D: col = lane&15, row = (lane>>4)*4 + reg)
  #pragma unroll
  for (int nf = 0; nf < 4; ++nf) {
    const int n = wn * 64 + nf * 16 + lr;
    const float bv = bias[n];
    #pragma unroll
    for (int mf = 0; mf < 4; ++mf) {
      #pragma unroll
      for (int j = 0; j < 4; ++j) {
        size_t m = m0 + mf * 16 + lg * 4 + j;
        U[m * Ksz + n] = acc[mf][nf][j] + bv;
      }
    }
  }
}

// --------- scan pass 1: per-chunk local carry from zero --------------------
__global__ __launch_bounds__(256) void scan_summary(
    const float* __restrict__ U, const float* __restrict__ consts,
    float* __restrict__ carry) {
  const int k = threadIdx.x;
  const int bm = blockIdx.x;   // b*NCH + m
  const float ar = consts[k], ai = consts[Ksz + k];
  const float* up = U + (size_t)bm * (CHUNK * Ksz) + k;
  float c = 0.f, s = 0.f;
  #pragma unroll 8
  for (int t = 0; t < CHUNK; ++t) {
    float u = up[(size_t)t * Ksz];
    float cn = fmaf(ar, c, fmaf(-ai, s, u));
    s = fmaf(ai, c, ar * s);
    c = cn;
  }
  ((float2*)carry)[(size_t)bm * Ksz + k] = make_float2(c, s);
}

// --------- scan pass 2: exclusive prefix over chunks (A = a^64) ------------
__global__ __launch_bounds__(64) void scan_prefix(
    const float* __restrict__ consts, const float* __restrict__ carry,
    float* __restrict__ prefix) {
  const int k = blockIdx.y * 64 + threadIdx.x;
  const int b = blockIdx.x;
  const float Ar = consts[2 * Ksz + k], Ai = consts[3 * Ksz + k];
  const float2* cp = (const float2*)carry;
  float2* pp = (float2*)prefix;
  float c = 0.f, s = 0.f;
  for (int m = 0; m < NCH; ++m) {
    const size_t idx = (size_t)(b * NCH + m) * Ksz + k;
    pp[idx] = make_float2(c, s);
    float2 L = cp[idx];
    float cn = fmaf(Ar, c, fmaf(-Ai, s, L.x));
    float sn = fmaf(Ai, c, fmaf(Ar, s, L.y));
    c = cn; s = sn;
  }
}

// --------- scan pass 3: rescan chunk from true carry, write output ---------
__global__ __launch_bounds__(256) void scan_final(
    const float* __restrict__ U, const float* __restrict__ consts,
    const float* __restrict__ prefix, float* __restrict__ out) {
  const int k = threadIdx.x;
  const int bm = blockIdx.x;
  const float ar = consts[k], ai = consts[Ksz + k];
  float2 w = ((const float2*)prefix)[(size_t)bm * Ksz + k];
  float c = w.x, s = w.y;
  const float* up = U + (size_t)bm * (CHUNK * Ksz) + k;
  float* op = out + (size_t)bm * (CHUNK * 2 * Ksz);
  #pragma unroll 4
  for (int t = 0; t < CHUNK; ++t) {
    float u = up[(size_t)t * Ksz];
    float cn = fmaf(ar, c, fmaf(-ai, s, u));
    s = fmaf(ai, c, ar * s);
    c = cn;
    op[(size_t)t * 2 * Ksz + k] = c;
    op[(size_t)t * 2 * Ksz + Ksz + k] = s;
  }
}

extern "C" void kernel_launch(void* const* d_in, const int* in_sizes, int n_in,
                              void* d_out, int out_size, void* d_ws, size_t ws_size,
                              hipStream_t stream) {
  const float* x    = (const float*)d_in[0];
  const float* srr  = (const float*)d_in[1];
  const float* sim  = (const float*)d_in[2];
  const float* traw = (const float*)d_in[3];
  const float* W    = (const float*)d_in[4];
  const float* bias = (const float*)d_in[5];
  float* out = (float*)d_out;

  // ws layout (floats): consts[2048] | U[65536*256] | carry | prefix | WfH | WfL
  float* wsf    = (float*)d_ws;
  float* consts = wsf;
  float* U      = wsf + 2048;
  float* carry  = U + (size_t)Msz * Ksz;                    // +16777216
  float* prefix = carry + (size_t)2 * Bsz * NCH * Ksz;      // +524288
  unsigned int* WfH = (unsigned int*)(prefix + (size_t)2 * Bsz * NCH * Ksz);
  unsigned int* WfL = WfH + 65536;

  prep_kernel<<<1, 512, 0, stream>>>(srr, sim, traw, W, consts);
  wpack_kernel<<<256, 64, 0, stream>>>(W, consts, WfH, WfL);
  gemm_mfma<<<Msz / 64, 256, 0, stream>>>(x, WfH, WfL, bias, U);
  scan_summary<<<Bsz * NCH, Ksz, 0, stream>>>(U, consts, carry);
  scan_prefix<<<dim3(Bsz, Ksz / 64), 64, 0, stream>>>(consts, carry, prefix);
  scan_final<<<Bsz * NCH, Ksz, 0, stream>>>(U, consts, prefix, out);
}

// Round 4
// 140.297 us; speedup vs baseline: 2.3042x; 1.1957x over previous
//
#include <hip/hip_runtime.h>

#define Bsz 16
#define Tsz 4096
#define Dsz 512
#define Ksz 256
#define Msz (Bsz * Tsz)      // 65536
#define CHUNK 64
#define NCH (Tsz / CHUNK)    // 64

typedef __attribute__((ext_vector_type(8))) short short8;
typedef __attribute__((ext_vector_type(4))) float f32x4;

// ---------------- threefry2x32 (key = (0, 42)) — matches JAX exactly -------
__device__ __forceinline__ unsigned int rotl32(unsigned int x, int d) {
  return (x << d) | (x >> (32 - d));
}

__device__ void threefry_pair(unsigned int c0, unsigned int c1,
                              unsigned int& o0, unsigned int& o1) {
  const unsigned int k0 = 0u, k1 = 42u;
  const unsigned int k2 = k0 ^ k1 ^ 0x1BD11BDAu;
  unsigned int x0 = c0 + k0;
  unsigned int x1 = c1 + k1;
#define TF_ROUND(r) { x0 += x1; x1 = rotl32(x1, (r)); x1 ^= x0; }
  TF_ROUND(13) TF_ROUND(15) TF_ROUND(26) TF_ROUND(6)
  x0 += k1; x1 += k2 + 1u;
  TF_ROUND(17) TF_ROUND(29) TF_ROUND(16) TF_ROUND(24)
  x0 += k2; x1 += k0 + 2u;
  TF_ROUND(13) TF_ROUND(15) TF_ROUND(26) TF_ROUND(6)
  x0 += k0; x1 += k1 + 3u;
  TF_ROUND(17) TF_ROUND(29) TF_ROUND(16) TF_ROUND(24)
  x0 += k1; x1 += k2 + 4u;
  TF_ROUND(13) TF_ROUND(15) TF_ROUND(26) TF_ROUND(6)
  x0 += k2; x1 += k0 + 5u;
#undef TF_ROUND
  o0 = x0; o1 = x1;
}

// XLA ErfInv32 polynomial (math.cc)
__device__ float erfinv32(float x) {
  float w = -log1pf(-x * x);
  float p;
  if (w < 5.f) {
    w -= 2.5f;
    p = 2.81022636e-08f;
    p = fmaf(p, w, 3.43273939e-07f);
    p = fmaf(p, w, -3.5233877e-06f);
    p = fmaf(p, w, -4.39150654e-06f);
    p = fmaf(p, w, 0.00021858087f);
    p = fmaf(p, w, -0.00125372503f);
    p = fmaf(p, w, -0.00417768164f);
    p = fmaf(p, w, 0.246640727f);
    p = fmaf(p, w, 1.50140941f);
  } else {
    w = sqrtf(w) - 3.f;
    p = -0.000200214257f;
    p = fmaf(p, w, 0.000100950558f);
    p = fmaf(p, w, 0.00134934322f);
    p = fmaf(p, w, -0.00367342844f);
    p = fmaf(p, w, 0.00573950773f);
    p = fmaf(p, w, -0.0076224613f);
    p = fmaf(p, w, 0.00943887047f);
    p = fmaf(p, w, 1.00167406f);
    p = fmaf(p, w, 2.83297682f);
  }
  return p * x;
}

// JAX: bits -> uniform[-0.99999994, 1) -> sqrt(2)*erfinv
__device__ float bits_to_normal(unsigned int bits) {
  unsigned int fb = (bits >> 9) | 0x3f800000u;
  float f = __uint_as_float(fb) - 1.0f;   // [0,1)
  const float lo = -0.99999994f;          // nextafter(-1, 0) in f32
  float u = f * 2.0f + lo;                // hi - lo rounds to exactly 2.0f
  u = fmaxf(lo, u);
  return 1.41421356f * erfinv32(u);
}

__device__ float block_sum_512(float v, float* s_red) {
  #pragma unroll
  for (int o = 32; o > 0; o >>= 1) v += __shfl_down(v, o);
  const int lane = threadIdx.x & 63, wid = threadIdx.x >> 6;
  if (lane == 0) s_red[wid] = v;
  __syncthreads();
  float r = 0.f;
  #pragma unroll
  for (int i = 0; i < 8; ++i) r += s_red[i];
  __syncthreads();
  return r;
}

__device__ __forceinline__ unsigned int bf16rne(float f) {
  unsigned int u = __float_as_uint(f);
  return (u + 0x7FFFu + ((u >> 16) & 1u)) >> 16;
}

// --------- prep1 (16 blocks x 512): partial_v[b][d] = sum_k W[k][d]*u0n[k] --
__global__ __launch_bounds__(512) void prep1_kernel(
    const float* __restrict__ W, float* __restrict__ partial_v) {
  __shared__ float s_u0[Ksz];
  __shared__ float s_red[8];
  const int tid = threadIdx.x;
  if (tid < 128) {
    unsigned int y0, y1;
    threefry_pair((unsigned int)tid, (unsigned int)(tid + 128), y0, y1);
    s_u0[tid] = bits_to_normal(y0);
    s_u0[tid + 128] = bits_to_normal(y1);
  }
  __syncthreads();
  float val = (tid < Ksz) ? s_u0[tid] * s_u0[tid] : 0.f;
  float ss = block_sum_512(val, s_red);
  float inv = 1.f / fmaxf(sqrtf(ss), 1e-7f);

  const int k0 = blockIdx.x * 16;
  float acc = 0.f;
  #pragma unroll
  for (int kk = 0; kk < 16; ++kk)
    acc = fmaf(W[(size_t)(k0 + kk) * Dsz + tid], s_u0[k0 + kk], acc);
  partial_v[blockIdx.x * Dsz + tid] = acc * inv;
}

// --------- prep2 (64 blocks x 512): v = normalize(sum partials); wv rows ---
__global__ __launch_bounds__(512) void prep2_kernel(
    const float* __restrict__ W, const float* __restrict__ partial_v,
    float* __restrict__ wv) {
  __shared__ float s_v[Dsz];
  __shared__ float s_red[8];
  __shared__ float s_p[8];
  const int tid = threadIdx.x;
  float acc = 0.f;
  #pragma unroll
  for (int b = 0; b < 16; ++b) acc += partial_v[b * Dsz + tid];
  float ssv = block_sum_512(acc * acc, s_red);
  float invv = 1.f / fmaxf(sqrtf(ssv), 1e-7f);
  s_v[tid] = acc * invv;
  __syncthreads();

  // 4 rows per block, 128 threads per row
  const int k = blockIdx.x * 4 + (tid >> 7);
  const int sub = tid & 127;
  const float* wr = W + (size_t)k * Dsz;
  float p = 0.f;
  #pragma unroll
  for (int j = sub; j < Dsz; j += 128) p = fmaf(wr[j], s_v[j], p);
  #pragma unroll
  for (int o = 32; o > 0; o >>= 1) p += __shfl_down(p, o);
  const int lane = tid & 63, wid = tid >> 6;
  if (lane == 0) s_p[wid] = p;
  __syncthreads();
  if (tid < 4) wv[blockIdx.x * 4 + tid] = s_p[2 * tid] + s_p[2 * tid + 1];
}

// --------- prep3 (1 block x 256): sigma + all per-k constants --------------
// consts layout (floats): [0]=ar [K]=ai [2K]=A64r [3K]=A64i [4K]=P4r [5K]=P4i
//                         [6K]=P8r [7K]=P8i [8K]=P16r [9K]=P16i [10K]=inv_sigma
__global__ __launch_bounds__(256) void prep3_kernel(
    const float* __restrict__ s_real_raw, const float* __restrict__ s_imag,
    const float* __restrict__ tau_raw, const float* __restrict__ wv,
    float* __restrict__ consts) {
  __shared__ float s_p[4];
  const int tid = threadIdx.x;
  float v = wv[tid];
  float v2 = v * v;
  #pragma unroll
  for (int o = 32; o > 0; o >>= 1) v2 += __shfl_down(v2, o);
  const int lane = tid & 63, wid = tid >> 6;
  if (lane == 0) s_p[wid] = v2;
  __syncthreads();
  float sswv = s_p[0] + s_p[1] + s_p[2] + s_p[3];
  float sigma = sswv / fmaxf(sqrtf(sswv), 1e-7f);
  if (tid == 0) consts[10 * Ksz] = 1.f / sigma;

  float tr = tau_raw[0];
  float tau = fmaxf(tr, 0.f) + log1pf(expf(-fabsf(tr))) + 1e-3f;
  float srr = s_real_raw[tid];
  float sp = fmaxf(srr, 0.f) + log1pf(expf(-fabsf(srr)));
  float alpha0 = (sp + 1e-6f) * tau;
  float omega0 = s_imag[tid] * tau;
  const float dt = 1.f / 4095.f;
  float ad = alpha0 * dt, an = omega0 * dt;
  consts[tid]            = expf(-ad) * cosf(an);
  consts[Ksz + tid]      = expf(-ad) * sinf(an);
  consts[2 * Ksz + tid]  = expf(-ad * 64.f) * cosf(an * 64.f);
  consts[3 * Ksz + tid]  = expf(-ad * 64.f) * sinf(an * 64.f);
  consts[4 * Ksz + tid]  = expf(-ad * 4.f) * cosf(an * 4.f);
  consts[5 * Ksz + tid]  = expf(-ad * 4.f) * sinf(an * 4.f);
  consts[6 * Ksz + tid]  = expf(-ad * 8.f) * cosf(an * 8.f);
  consts[7 * Ksz + tid]  = expf(-ad * 8.f) * sinf(an * 8.f);
  consts[8 * Ksz + tid]  = expf(-ad * 16.f) * cosf(an * 16.f);
  consts[9 * Ksz + tid]  = expf(-ad * 16.f) * sinf(an * 16.f);
}

// --------- wpack: W/sigma -> bf16 h/l in MFMA B-fragment order -------------
__global__ __launch_bounds__(64) void wpack_kernel(
    const float* __restrict__ W, const float* __restrict__ consts,
    unsigned int* __restrict__ WfH, unsigned int* __restrict__ WfL) {
  const int kb = blockIdx.x >> 4;
  const int nb = blockIdx.x & 15;
  const int lane = threadIdx.x;
  const int lr = lane & 15, lg = lane >> 4;
  const float inv_sigma = consts[10 * Ksz];
  const float* src = W + (size_t)(nb * 16 + lr) * Dsz + kb * 32 + lg * 8;
  float v[8];
  *(float4*)&v[0] = *(const float4*)src;
  *(float4*)&v[4] = *(const float4*)(src + 4);
  unsigned int hh[4], ll[4];
  #pragma unroll
  for (int i = 0; i < 4; ++i) {
    float v0 = v[2 * i] * inv_sigma, v1 = v[2 * i + 1] * inv_sigma;
    unsigned int u0 = __float_as_uint(v0);
    unsigned int u1 = __float_as_uint(v1);
    hh[i] = (u0 >> 16) | (u1 & 0xFFFF0000u);
    float r0 = v0 - __uint_as_float(u0 & 0xFFFF0000u);
    float r1 = v1 - __uint_as_float(u1 & 0xFFFF0000u);
    ll[i] = bf16rne(r0) | (bf16rne(r1) << 16);
  }
  const size_t off = (size_t)blockIdx.x * 256 + lane * 4;   // in uints
  *(int4*)(WfH + off) = *(int4*)hh;
  *(int4*)(WfL + off) = *(int4*)ll;
}

// --------- MFMA GEMM + fused chunk-scan carry ------------------------------
// BM=64 (= one scan chunk), BN=256, BK=32, 256 thr = 4 waves (wn 0..3).
// A: f32->bf16 h/l, 2-deep global prefetch, dbuf LDS, XOR-swizzled.
// B: pre-packed bf16 frags straight from L2.
// Epilogue: U store + carry_k = sum_t a^(63-t) u_t (per-lane weighted sum,
// shfl-reduced over the 4 k-groups).
__global__ __launch_bounds__(256, 3) void gemm_mfma(
    const float* __restrict__ X, const unsigned int* __restrict__ WfH,
    const unsigned int* __restrict__ WfL, const float* __restrict__ bias,
    const float* __restrict__ consts, float* __restrict__ U,
    float* __restrict__ carry) {
  __shared__ unsigned int ldsA[2][2048];   // 2 x 8KB

  const int tid = threadIdx.x;
  const size_t m0 = (size_t)blockIdx.x * 64;

  const int sr = tid >> 2;              // 0..63
  const int sc = (tid & 3) * 8;
  const float* gx = X + (m0 + sr) * Dsz + sc;
  const int swz = (sr & 7) << 4;
  const int aoff_h = sr * 128 + ((sc * 2) ^ swz);
  const int aoff_l = sr * 128 + ((64 + sc * 2) ^ swz);

  const int lane = tid & 63;
  const int wn = tid >> 6;
  const int lr = lane & 15;
  const int lg = lane >> 4;

  float xaA[8], xaB[8];
  #define LOAD_A(dst, kb) do {                             \
    const float* p = gx + (kb) * 32;                       \
    *(float4*)&dst[0] = *(const float4*)p;                 \
    *(float4*)&dst[4] = *(const float4*)(p + 4);           \
  } while (0)

  LOAD_A(xaA, 0);
  LOAD_A(xaB, 1);

  f32x4 acc[4][4];
  #pragma unroll
  for (int i = 0; i < 4; ++i)
    #pragma unroll
    for (int j = 0; j < 4; ++j) acc[i][j] = (f32x4)(0.f);

  const char* const wfh = (const char*)WfH + (size_t)wn * 4096 + lane * 16;
  const char* const wfl = (const char*)WfL + (size_t)wn * 4096 + lane * 16;

  #define BODY(kb, xa) do {                                                  \
    char* const Ab = (char*)ldsA[(kb) & 1];                                  \
    /* B fragments first (independent of xa's vmcnt wait) */                 \
    short8 bh[4], bl[4];                                                     \
    {                                                                        \
      const size_t tb = (size_t)(kb) * 16384;                                \
      _Pragma("unroll")                                                      \
      for (int f = 0; f < 4; ++f) {                                          \
        bh[f] = *(const short8*)(wfh + tb + (size_t)f * 1024);               \
        bl[f] = *(const short8*)(wfl + tb + (size_t)f * 1024);               \
      }                                                                      \
    }                                                                        \
    /* split-convert A (waits on xa's load from 2 iters ago) */              \
    {                                                                        \
      unsigned int hh[4], llw[4];                                            \
      _Pragma("unroll")                                                      \
      for (int i = 0; i < 4; ++i) {                                          \
        float v0 = xa[2 * i], v1 = xa[2 * i + 1];                            \
        unsigned int u0 = __float_as_uint(v0);                               \
        unsigned int u1 = __float_as_uint(v1);                               \
        hh[i] = (u0 >> 16) | (u1 & 0xFFFF0000u);                             \
        float r0 = v0 - __uint_as_float(u0 & 0xFFFF0000u);                   \
        float r1 = v1 - __uint_as_float(u1 & 0xFFFF0000u);                   \
        llw[i] = bf16rne(r0) | (bf16rne(r1) << 16);                          \
      }                                                                      \
      *(int4*)(Ab + aoff_h) = *(int4*)hh;                                    \
      *(int4*)(Ab + aoff_l) = *(int4*)llw;                                   \
    }                                                                        \
    if ((kb) + 2 < 16) LOAD_A(xa, (kb) + 2);   /* 2-deep prefetch */         \
    asm volatile("s_waitcnt lgkmcnt(0)" ::: "memory");                       \
    __builtin_amdgcn_s_barrier();                                            \
    __builtin_amdgcn_sched_barrier(0);                                       \
    short8 ah[4], al[4];                                                     \
    _Pragma("unroll")                                                        \
    for (int f = 0; f < 4; ++f) {                                            \
      const int r = f * 16 + lr;                                             \
      const int sz = (r & 7) << 4;                                           \
      ah[f] = *(const short8*)(Ab + r * 128 + ((lg * 16) ^ sz));             \
      al[f] = *(const short8*)(Ab + r * 128 + ((64 + lg * 16) ^ sz));        \
    }                                                                        \
    _Pragma("unroll")                                                        \
    for (int mf = 0; mf < 4; ++mf)                                           \
      _Pragma("unroll")                                                      \
      for (int nf = 0; nf < 4; ++nf)                                         \
        acc[mf][nf] = __builtin_amdgcn_mfma_f32_16x16x32_bf16(               \
            ah[mf], bh[nf], acc[mf][nf], 0, 0, 0);                           \
    _Pragma("unroll")                                                        \
    for (int mf = 0; mf < 4; ++mf)                                           \
      _Pragma("unroll")                                                      \
      for (int nf = 0; nf < 4; ++nf)                                         \
        acc[mf][nf] = __builtin_amdgcn_mfma_f32_16x16x32_bf16(               \
            ah[mf], bl[nf], acc[mf][nf], 0, 0, 0);                           \
    _Pragma("unroll")                                                        \
    for (int mf = 0; mf < 4; ++mf)                                           \
      _Pragma("unroll")                                                      \
      for (int nf = 0; nf < 4; ++nf)                                         \
        acc[mf][nf] = __builtin_amdgcn_mfma_f32_16x16x32_bf16(               \
            al[mf], bh[nf], acc[mf][nf], 0, 0, 0);                           \
  } while (0)

  for (int kb = 0; kb < 16; kb += 2) {
    BODY(kb, xaA);
    BODY(kb + 1, xaB);
  }
  #undef BODY
  #undef LOAD_A

  // ---- epilogue: U store + fused chunk carry ----
  // u_t at t = mf*16 + lg*4 + j; weight a^{63-t} = P4^{3-lg} * P16^{3-mf} * a^{3-j}
  #pragma unroll
  for (int nf = 0; nf < 4; ++nf) {
    const int n = wn * 64 + nf * 16 + lr;
    const float bv = bias[n];
    const float ar_ = consts[n],           ai_ = consts[Ksz + n];
    const float p4r = consts[4 * Ksz + n], p4i = consts[5 * Ksz + n];
    const float p8r = consts[6 * Ksz + n], p8i = consts[7 * Ksz + n];
    const float p16r = consts[8 * Ksz + n], p16i = consts[9 * Ksz + n];
    const int e = 3 - lg;
    const float b1r = (e & 1) ? p4r : 1.f, b1i = (e & 1) ? p4i : 0.f;
    const float b2r = (e & 2) ? p8r : 1.f, b2i = (e & 2) ? p8i : 0.f;
    float wr = b1r * b2r - b1i * b2i;
    float wi = b1r * b2i + b1i * b2r;
    float Sr = 0.f, Si = 0.f;
    #pragma unroll
    for (int mf = 3; mf >= 0; --mf) {
      float vr = wr, vi = wi;
      #pragma unroll
      for (int j = 3; j >= 0; --j) {
        const float u = acc[mf][nf][j] + bv;
        U[(m0 + mf * 16 + lg * 4 + j) * Ksz + n] = u;
        Sr = fmaf(u, vr, Sr);
        Si = fmaf(u, vi, Si);
        if (j) {
          float t_ = vr * ar_ - vi * ai_;
          vi = vr * ai_ + vi * ar_;
          vr = t_;
        }
      }
      if (mf) {
        float t_ = wr * p16r - wi * p16i;
        wi = wr * p16i + wi * p16r;
        wr = t_;
      }
    }
    Sr += __shfl_xor(Sr, 16); Si += __shfl_xor(Si, 16);
    Sr += __shfl_xor(Sr, 32); Si += __shfl_xor(Si, 32);
    if (lg == 0)
      ((float2*)carry)[(size_t)blockIdx.x * Ksz + n] = make_float2(Sr, Si);
  }
}

// --------- scan pass 2: exclusive prefix over chunks (A = a^64) ------------
__global__ __launch_bounds__(64) void scan_prefix(
    const float* __restrict__ consts, const float* __restrict__ carry,
    float* __restrict__ prefix) {
  const int k = blockIdx.y * 64 + threadIdx.x;
  const int b = blockIdx.x;
  const float Ar = consts[2 * Ksz + k], Ai = consts[3 * Ksz + k];
  const float2* cp = (const float2*)carry;
  float2* pp = (float2*)prefix;
  float c = 0.f, s = 0.f;
  for (int m = 0; m < NCH; ++m) {
    const size_t idx = (size_t)(b * NCH + m) * Ksz + k;
    pp[idx] = make_float2(c, s);
    float2 L = cp[idx];
    float cn = fmaf(Ar, c, fmaf(-Ai, s, L.x));
    float sn = fmaf(Ai, c, fmaf(Ar, s, L.y));
    c = cn; s = sn;
  }
}

// --------- scan pass 3: rescan chunk from true carry, write output ---------
__global__ __launch_bounds__(256) void scan_final(
    const float* __restrict__ U, const float* __restrict__ consts,
    const float* __restrict__ prefix, float* __restrict__ out) {
  const int k = threadIdx.x;
  const int bm = blockIdx.x;
  const float ar = consts[k], ai = consts[Ksz + k];
  float2 w = ((const float2*)prefix)[(size_t)bm * Ksz + k];
  float c = w.x, s = w.y;
  const float* up = U + (size_t)bm * (CHUNK * Ksz) + k;
  float* op = out + (size_t)bm * (CHUNK * 2 * Ksz);
  #pragma unroll 4
  for (int t = 0; t < CHUNK; ++t) {
    float u = up[(size_t)t * Ksz];
    float cn = fmaf(ar, c, fmaf(-ai, s, u));
    s = fmaf(ai, c, ar * s);
    c = cn;
    op[(size_t)t * 2 * Ksz + k] = c;
    op[(size_t)t * 2 * Ksz + Ksz + k] = s;
  }
}

extern "C" void kernel_launch(void* const* d_in, const int* in_sizes, int n_in,
                              void* d_out, int out_size, void* d_ws, size_t ws_size,
                              hipStream_t stream) {
  const float* x    = (const float*)d_in[0];
  const float* srr  = (const float*)d_in[1];
  const float* sim  = (const float*)d_in[2];
  const float* traw = (const float*)d_in[3];
  const float* W    = (const float*)d_in[4];
  const float* bias = (const float*)d_in[5];
  float* out = (float*)d_out;

  // ws layout (floats): consts[4096] | U[16777216] | carry[524288] |
  //   prefix[524288] | WfH[65536] | WfL[65536] | partial_v[8192] | wv[256]
  float* wsf    = (float*)d_ws;
  float* consts = wsf;
  float* U      = wsf + 4096;
  float* carry  = U + (size_t)Msz * Ksz;
  float* prefix = carry + (size_t)2 * Bsz * NCH * Ksz;
  unsigned int* WfH = (unsigned int*)(prefix + (size_t)2 * Bsz * NCH * Ksz);
  unsigned int* WfL = WfH + 65536;
  float* partial_v  = (float*)(WfL + 65536);
  float* wv         = partial_v + 16 * Dsz;

  prep1_kernel<<<16, 512, 0, stream>>>(W, partial_v);
  prep2_kernel<<<64, 512, 0, stream>>>(W, partial_v, wv);
  prep3_kernel<<<1, 256, 0, stream>>>(srr, sim, traw, wv, consts);
  wpack_kernel<<<256, 64, 0, stream>>>(W, consts, WfH, WfL);
  gemm_mfma<<<Msz / 64, 256, 0, stream>>>(x, WfH, WfL, bias, consts, U, carry);
  scan_prefix<<<dim3(Bsz, Ksz / 64), 64, 0, stream>>>(consts, carry, prefix);
  scan_final<<<Bsz * NCH, Ksz, 0, stream>>>(U, consts, prefix, out);
}

// Round 5
// 124.750 us; speedup vs baseline: 2.5913x; 1.1246x over previous
//
#include <hip/hip_runtime.h>

#define Bsz 16
#define Tsz 4096
#define Dsz 512
#define Ksz 256
#define Msz (Bsz * Tsz)      // 65536
#define CHUNK 64
#define NCH (Tsz / CHUNK)    // 64

typedef __attribute__((ext_vector_type(8))) short short8;
typedef __attribute__((ext_vector_type(4))) float f32x4;

// ---------------- threefry2x32 (key = (0, 42)) — matches JAX exactly -------
__device__ __forceinline__ unsigned int rotl32(unsigned int x, int d) {
  return (x << d) | (x >> (32 - d));
}

__device__ void threefry_pair(unsigned int c0, unsigned int c1,
                              unsigned int& o0, unsigned int& o1) {
  const unsigned int k0 = 0u, k1 = 42u;
  const unsigned int k2 = k0 ^ k1 ^ 0x1BD11BDAu;
  unsigned int x0 = c0 + k0;
  unsigned int x1 = c1 + k1;
#define TF_ROUND(r) { x0 += x1; x1 = rotl32(x1, (r)); x1 ^= x0; }
  TF_ROUND(13) TF_ROUND(15) TF_ROUND(26) TF_ROUND(6)
  x0 += k1; x1 += k2 + 1u;
  TF_ROUND(17) TF_ROUND(29) TF_ROUND(16) TF_ROUND(24)
  x0 += k2; x1 += k0 + 2u;
  TF_ROUND(13) TF_ROUND(15) TF_ROUND(26) TF_ROUND(6)
  x0 += k0; x1 += k1 + 3u;
  TF_ROUND(17) TF_ROUND(29) TF_ROUND(16) TF_ROUND(24)
  x0 += k1; x1 += k2 + 4u;
  TF_ROUND(13) TF_ROUND(15) TF_ROUND(26) TF_ROUND(6)
  x0 += k2; x1 += k0 + 5u;
#undef TF_ROUND
  o0 = x0; o1 = x1;
}

// XLA ErfInv32 polynomial (math.cc)
__device__ float erfinv32(float x) {
  float w = -log1pf(-x * x);
  float p;
  if (w < 5.f) {
    w -= 2.5f;
    p = 2.81022636e-08f;
    p = fmaf(p, w, 3.43273939e-07f);
    p = fmaf(p, w, -3.5233877e-06f);
    p = fmaf(p, w, -4.39150654e-06f);
    p = fmaf(p, w, 0.00021858087f);
    p = fmaf(p, w, -0.00125372503f);
    p = fmaf(p, w, -0.00417768164f);
    p = fmaf(p, w, 0.246640727f);
    p = fmaf(p, w, 1.50140941f);
  } else {
    w = sqrtf(w) - 3.f;
    p = -0.000200214257f;
    p = fmaf(p, w, 0.000100950558f);
    p = fmaf(p, w, 0.00134934322f);
    p = fmaf(p, w, -0.00367342844f);
    p = fmaf(p, w, 0.00573950773f);
    p = fmaf(p, w, -0.0076224613f);
    p = fmaf(p, w, 0.00943887047f);
    p = fmaf(p, w, 1.00167406f);
    p = fmaf(p, w, 2.83297682f);
  }
  return p * x;
}

// JAX: bits -> uniform[-0.99999994, 1) -> sqrt(2)*erfinv
__device__ float bits_to_normal(unsigned int bits) {
  unsigned int fb = (bits >> 9) | 0x3f800000u;
  float f = __uint_as_float(fb) - 1.0f;   // [0,1)
  const float lo = -0.99999994f;          // nextafter(-1, 0) in f32
  float u = f * 2.0f + lo;                // hi - lo rounds to exactly 2.0f
  u = fmaxf(lo, u);
  return 1.41421356f * erfinv32(u);
}

__device__ float block_sum_512(float v, float* s_red) {
  #pragma unroll
  for (int o = 32; o > 0; o >>= 1) v += __shfl_down(v, o);
  const int lane = threadIdx.x & 63, wid = threadIdx.x >> 6;
  if (lane == 0) s_red[wid] = v;
  __syncthreads();
  float r = 0.f;
  #pragma unroll
  for (int i = 0; i < 8; ++i) r += s_red[i];
  __syncthreads();
  return r;
}

__device__ __forceinline__ unsigned int bf16rne(float f) {
  unsigned int u = __float_as_uint(f);
  return (u + 0x7FFFu + ((u >> 16) & 1u)) >> 16;
}

// --------- prep1 (16 blocks x 512): partial_v[b][d] = sum_k W[k][d]*u0n[k] --
__global__ __launch_bounds__(512) void prep1_kernel(
    const float* __restrict__ W, float* __restrict__ partial_v) {
  __shared__ float s_u0[Ksz];
  __shared__ float s_red[8];
  const int tid = threadIdx.x;
  if (tid < 128) {
    unsigned int y0, y1;
    threefry_pair((unsigned int)tid, (unsigned int)(tid + 128), y0, y1);
    s_u0[tid] = bits_to_normal(y0);
    s_u0[tid + 128] = bits_to_normal(y1);
  }
  __syncthreads();
  float val = (tid < Ksz) ? s_u0[tid] * s_u0[tid] : 0.f;
  float ss = block_sum_512(val, s_red);
  float inv = 1.f / fmaxf(sqrtf(ss), 1e-7f);

  const int k0 = blockIdx.x * 16;
  float acc = 0.f;
  #pragma unroll
  for (int kk = 0; kk < 16; ++kk)
    acc = fmaf(W[(size_t)(k0 + kk) * Dsz + tid], s_u0[k0 + kk], acc);
  partial_v[blockIdx.x * Dsz + tid] = acc * inv;
}

// --------- prep2 (64 blocks x 512): v = normalize(sum partials); wv rows ---
__global__ __launch_bounds__(512) void prep2_kernel(
    const float* __restrict__ W, const float* __restrict__ partial_v,
    float* __restrict__ wv) {
  __shared__ float s_v[Dsz];
  __shared__ float s_red[8];
  __shared__ float s_p[8];
  const int tid = threadIdx.x;
  float acc = 0.f;
  #pragma unroll
  for (int b = 0; b < 16; ++b) acc += partial_v[b * Dsz + tid];
  float ssv = block_sum_512(acc * acc, s_red);
  float invv = 1.f / fmaxf(sqrtf(ssv), 1e-7f);
  s_v[tid] = acc * invv;
  __syncthreads();

  // 4 rows per block, 128 threads per row
  const int k = blockIdx.x * 4 + (tid >> 7);
  const int sub = tid & 127;
  const float* wr = W + (size_t)k * Dsz;
  float p = 0.f;
  #pragma unroll
  for (int j = sub; j < Dsz; j += 128) p = fmaf(wr[j], s_v[j], p);
  #pragma unroll
  for (int o = 32; o > 0; o >>= 1) p += __shfl_down(p, o);
  const int lane = tid & 63, wid = tid >> 6;
  if (lane == 0) s_p[wid] = p;
  __syncthreads();
  if (tid < 4) wv[blockIdx.x * 4 + tid] = s_p[2 * tid] + s_p[2 * tid + 1];
}

// --------- prep3 (1 block x 256): sigma + all per-k constants --------------
// consts layout (floats): [0]=ar [K]=ai [2K]=A64r [3K]=A64i [4K]=P4r [5K]=P4i
//                         [6K]=P8r [7K]=P8i [8K]=P16r [9K]=P16i [10K]=inv_sigma
__global__ __launch_bounds__(256) void prep3_kernel(
    const float* __restrict__ s_real_raw, const float* __restrict__ s_imag,
    const float* __restrict__ tau_raw, const float* __restrict__ wv,
    float* __restrict__ consts) {
  __shared__ float s_p[4];
  const int tid = threadIdx.x;
  float v = wv[tid];
  float v2 = v * v;
  #pragma unroll
  for (int o = 32; o > 0; o >>= 1) v2 += __shfl_down(v2, o);
  const int lane = tid & 63, wid = tid >> 6;
  if (lane == 0) s_p[wid] = v2;
  __syncthreads();
  float sswv = s_p[0] + s_p[1] + s_p[2] + s_p[3];
  float sigma = sswv / fmaxf(sqrtf(sswv), 1e-7f);
  if (tid == 0) consts[10 * Ksz] = 1.f / sigma;

  float tr = tau_raw[0];
  float tau = fmaxf(tr, 0.f) + log1pf(expf(-fabsf(tr))) + 1e-3f;
  float srr = s_real_raw[tid];
  float sp = fmaxf(srr, 0.f) + log1pf(expf(-fabsf(srr)));
  float alpha0 = (sp + 1e-6f) * tau;
  float omega0 = s_imag[tid] * tau;
  const float dt = 1.f / 4095.f;
  float ad = alpha0 * dt, an = omega0 * dt;
  consts[tid]            = expf(-ad) * cosf(an);
  consts[Ksz + tid]      = expf(-ad) * sinf(an);
  consts[2 * Ksz + tid]  = expf(-ad * 64.f) * cosf(an * 64.f);
  consts[3 * Ksz + tid]  = expf(-ad * 64.f) * sinf(an * 64.f);
  consts[4 * Ksz + tid]  = expf(-ad * 4.f) * cosf(an * 4.f);
  consts[5 * Ksz + tid]  = expf(-ad * 4.f) * sinf(an * 4.f);
  consts[6 * Ksz + tid]  = expf(-ad * 8.f) * cosf(an * 8.f);
  consts[7 * Ksz + tid]  = expf(-ad * 8.f) * sinf(an * 8.f);
  consts[8 * Ksz + tid]  = expf(-ad * 16.f) * cosf(an * 16.f);
  consts[9 * Ksz + tid]  = expf(-ad * 16.f) * sinf(an * 16.f);
}

// --------- wpack: W/sigma -> bf16 h/l in MFMA B-fragment order -------------
__global__ __launch_bounds__(64) void wpack_kernel(
    const float* __restrict__ W, const float* __restrict__ consts,
    unsigned int* __restrict__ WfH, unsigned int* __restrict__ WfL) {
  const int kb = blockIdx.x >> 4;
  const int nb = blockIdx.x & 15;
  const int lane = threadIdx.x;
  const int lr = lane & 15, lg = lane >> 4;
  const float inv_sigma = consts[10 * Ksz];
  const float* src = W + (size_t)(nb * 16 + lr) * Dsz + kb * 32 + lg * 8;
  float v[8];
  *(float4*)&v[0] = *(const float4*)src;
  *(float4*)&v[4] = *(const float4*)(src + 4);
  unsigned int hh[4], ll[4];
  #pragma unroll
  for (int i = 0; i < 4; ++i) {
    float v0 = v[2 * i] * inv_sigma, v1 = v[2 * i + 1] * inv_sigma;
    unsigned int u0 = __float_as_uint(v0);
    unsigned int u1 = __float_as_uint(v1);
    hh[i] = (u0 >> 16) | (u1 & 0xFFFF0000u);
    float r0 = v0 - __uint_as_float(u0 & 0xFFFF0000u);
    float r1 = v1 - __uint_as_float(u1 & 0xFFFF0000u);
    ll[i] = bf16rne(r0) | (bf16rne(r1) << 16);
  }
  const size_t off = (size_t)blockIdx.x * 256 + lane * 4;   // in uints
  *(int4*)(WfH + off) = *(int4*)hh;
  *(int4*)(WfL + off) = *(int4*)ll;
}

// --------- MFMA GEMM + fused chunk-scan carry ------------------------------
// BM=64 (= one scan chunk), BN=256, BK=32, 256 thr = 4 waves (wn 0..3).
// A: f32->bf16 h/l, 2-deep global reg prefetch, dbuf LDS, XOR-swizzled.
// B: pre-packed bf16 frags, 1-iter-ahead DOUBLE-BUFFERED register prefetch
//    (the round-4 bottleneck: same-iter B loads exposed L2 latency each step).
// Epilogue: U store + carry_k = sum_t a^(63-t) u_t (shfl-reduced).
__global__ __launch_bounds__(256, 2) void gemm_mfma(
    const float* __restrict__ X, const unsigned int* __restrict__ WfH,
    const unsigned int* __restrict__ WfL, const float* __restrict__ bias,
    const float* __restrict__ consts, float* __restrict__ U,
    float* __restrict__ carry) {
  __shared__ unsigned int ldsA[2][2048];   // 2 x 8KB

  const int tid = threadIdx.x;
  const size_t m0 = (size_t)blockIdx.x * 64;

  const int sr = tid >> 2;              // 0..63
  const int sc = (tid & 3) * 8;
  const float* gx = X + (m0 + sr) * Dsz + sc;
  const int swz = (sr & 7) << 4;
  const int aoff_h = sr * 128 + ((sc * 2) ^ swz);
  const int aoff_l = sr * 128 + ((64 + sc * 2) ^ swz);

  const int lane = tid & 63;
  const int wn = tid >> 6;
  const int lr = lane & 15;
  const int lg = lane >> 4;

  float xaA[8], xaB[8];
  #define LOAD_A(dst, kb) do {                             \
    const float* p = gx + (kb) * 32;                       \
    *(float4*)&dst[0] = *(const float4*)p;                 \
    *(float4*)&dst[4] = *(const float4*)(p + 4);           \
  } while (0)

  const char* const wfh = (const char*)WfH + (size_t)wn * 4096 + lane * 16;
  const char* const wfl = (const char*)WfL + (size_t)wn * 4096 + lane * 16;

  short8 bhA[4], blA[4], bhB[4], blB[4];
  #define LOAD_B(bh_, bl_, kb) do {                                          \
    const size_t tb = (size_t)(kb) * 16384;                                  \
    _Pragma("unroll")                                                        \
    for (int f = 0; f < 4; ++f) {                                            \
      bh_[f] = *(const short8*)(wfh + tb + (size_t)f * 1024);                \
      bl_[f] = *(const short8*)(wfl + tb + (size_t)f * 1024);                \
    }                                                                        \
  } while (0)

  LOAD_A(xaA, 0);
  LOAD_A(xaB, 1);
  LOAD_B(bhA, blA, 0);

  f32x4 acc[4][4];
  #pragma unroll
  for (int i = 0; i < 4; ++i)
    #pragma unroll
    for (int j = 0; j < 4; ++j) acc[i][j] = (f32x4)(0.f);

  // Body kb: consumes B-cur (loaded iter kb-1), prefetches B(kb+1) into
  // B-next; converts xa (loaded iter kb-2), prefetches A(kb+2) into xa.
  #define BODY(kb, xa, bhC, blC, bhN, blN) do {                              \
    char* const Ab = (char*)ldsA[(kb) & 1];                                  \
    if ((kb) + 1 < 16) LOAD_B(bhN, blN, (kb) + 1);   /* issue B early */     \
    /* split-convert A (waits on xa's load from 2 iters ago) */              \
    {                                                                        \
      unsigned int hh[4], llw[4];                                            \
      _Pragma("unroll")                                                      \
      for (int i = 0; i < 4; ++i) {                                          \
        float v0 = xa[2 * i], v1 = xa[2 * i + 1];                            \
        unsigned int u0 = __float_as_uint(v0);                               \
        unsigned int u1 = __float_as_uint(v1);                               \
        hh[i] = (u0 >> 16) | (u1 & 0xFFFF0000u);                             \
        float r0 = v0 - __uint_as_float(u0 & 0xFFFF0000u);                   \
        float r1 = v1 - __uint_as_float(u1 & 0xFFFF0000u);                   \
        llw[i] = bf16rne(r0) | (bf16rne(r1) << 16);                          \
      }                                                                      \
      *(int4*)(Ab + aoff_h) = *(int4*)hh;                                    \
      *(int4*)(Ab + aoff_l) = *(int4*)llw;                                   \
    }                                                                        \
    if ((kb) + 2 < 16) LOAD_A(xa, (kb) + 2);   /* 2-deep A prefetch */       \
    asm volatile("s_waitcnt lgkmcnt(0)" ::: "memory");                       \
    __builtin_amdgcn_s_barrier();                                            \
    __builtin_amdgcn_sched_barrier(0);                                       \
    short8 ah[4], al[4];                                                     \
    _Pragma("unroll")                                                        \
    for (int f = 0; f < 4; ++f) {                                            \
      const int r = f * 16 + lr;                                             \
      const int sz = (r & 7) << 4;                                           \
      ah[f] = *(const short8*)(Ab + r * 128 + ((lg * 16) ^ sz));             \
      al[f] = *(const short8*)(Ab + r * 128 + ((64 + lg * 16) ^ sz));        \
    }                                                                        \
    _Pragma("unroll")                                                        \
    for (int mf = 0; mf < 4; ++mf)                                           \
      _Pragma("unroll")                                                      \
      for (int nf = 0; nf < 4; ++nf)                                         \
        acc[mf][nf] = __builtin_amdgcn_mfma_f32_16x16x32_bf16(               \
            ah[mf], bhC[nf], acc[mf][nf], 0, 0, 0);                          \
    _Pragma("unroll")                                                        \
    for (int mf = 0; mf < 4; ++mf)                                           \
      _Pragma("unroll")                                                      \
      for (int nf = 0; nf < 4; ++nf)                                         \
        acc[mf][nf] = __builtin_amdgcn_mfma_f32_16x16x32_bf16(               \
            ah[mf], blC[nf], acc[mf][nf], 0, 0, 0);                          \
    _Pragma("unroll")                                                        \
    for (int mf = 0; mf < 4; ++mf)                                           \
      _Pragma("unroll")                                                      \
      for (int nf = 0; nf < 4; ++nf)                                         \
        acc[mf][nf] = __builtin_amdgcn_mfma_f32_16x16x32_bf16(               \
            al[mf], bhC[nf], acc[mf][nf], 0, 0, 0);                          \
  } while (0)

  for (int kb = 0; kb < 16; kb += 2) {
    BODY(kb,     xaA, bhA, blA, bhB, blB);
    BODY(kb + 1, xaB, bhB, blB, bhA, blA);
  }
  #undef BODY
  #undef LOAD_B
  #undef LOAD_A

  // ---- epilogue: U store + fused chunk carry ----
  // u_t at t = mf*16 + lg*4 + j; weight a^{63-t} = P4^{3-lg} * P16^{3-mf} * a^{3-j}
  #pragma unroll
  for (int nf = 0; nf < 4; ++nf) {
    const int n = wn * 64 + nf * 16 + lr;
    const float bv = bias[n];
    const float ar_ = consts[n],           ai_ = consts[Ksz + n];
    const float p4r = consts[4 * Ksz + n], p4i = consts[5 * Ksz + n];
    const float p8r = consts[6 * Ksz + n], p8i = consts[7 * Ksz + n];
    const float p16r = consts[8 * Ksz + n], p16i = consts[9 * Ksz + n];
    const int e = 3 - lg;
    const float b1r = (e & 1) ? p4r : 1.f, b1i = (e & 1) ? p4i : 0.f;
    const float b2r = (e & 2) ? p8r : 1.f, b2i = (e & 2) ? p8i : 0.f;
    float wr = b1r * b2r - b1i * b2i;
    float wi = b1r * b2i + b1i * b2r;
    float Sr = 0.f, Si = 0.f;
    #pragma unroll
    for (int mf = 3; mf >= 0; --mf) {
      float vr = wr, vi = wi;
      #pragma unroll
      for (int j = 3; j >= 0; --j) {
        const float u = acc[mf][nf][j] + bv;
        U[(m0 + mf * 16 + lg * 4 + j) * Ksz + n] = u;
        Sr = fmaf(u, vr, Sr);
        Si = fmaf(u, vi, Si);
        if (j) {
          float t_ = vr * ar_ - vi * ai_;
          vi = vr * ai_ + vi * ar_;
          vr = t_;
        }
      }
      if (mf) {
        float t_ = wr * p16r - wi * p16i;
        wi = wr * p16i + wi * p16r;
        wr = t_;
      }
    }
    Sr += __shfl_xor(Sr, 16); Si += __shfl_xor(Si, 16);
    Sr += __shfl_xor(Sr, 32); Si += __shfl_xor(Si, 32);
    if (lg == 0)
      ((float2*)carry)[(size_t)blockIdx.x * Ksz + n] = make_float2(Sr, Si);
  }
}

// --------- scan pass 2: exclusive prefix over chunks (A = a^64) ------------
__global__ __launch_bounds__(64) void scan_prefix(
    const float* __restrict__ consts, const float* __restrict__ carry,
    float* __restrict__ prefix) {
  const int k = blockIdx.y * 64 + threadIdx.x;
  const int b = blockIdx.x;
  const float Ar = consts[2 * Ksz + k], Ai = consts[3 * Ksz + k];
  const float2* cp = (const float2*)carry;
  float2* pp = (float2*)prefix;
  float c = 0.f, s = 0.f;
  for (int m = 0; m < NCH; ++m) {
    const size_t idx = (size_t)(b * NCH + m) * Ksz + k;
    pp[idx] = make_float2(c, s);
    float2 L = cp[idx];
    float cn = fmaf(Ar, c, fmaf(-Ai, s, L.x));
    float sn = fmaf(Ai, c, fmaf(Ar, s, L.y));
    c = cn; s = sn;
  }
}

// --------- scan pass 3: rescan chunk from true carry, write output ---------
__global__ __launch_bounds__(256) void scan_final(
    const float* __restrict__ U, const float* __restrict__ consts,
    const float* __restrict__ prefix, float* __restrict__ out) {
  const int k = threadIdx.x;
  const int bm = blockIdx.x;
  const float ar = consts[k], ai = consts[Ksz + k];
  float2 w = ((const float2*)prefix)[(size_t)bm * Ksz + k];
  float c = w.x, s = w.y;
  const float* up = U + (size_t)bm * (CHUNK * Ksz) + k;
  float* op = out + (size_t)bm * (CHUNK * 2 * Ksz);
  #pragma unroll 4
  for (int t = 0; t < CHUNK; ++t) {
    float u = up[(size_t)t * Ksz];
    float cn = fmaf(ar, c, fmaf(-ai, s, u));
    s = fmaf(ai, c, ar * s);
    c = cn;
    op[(size_t)t * 2 * Ksz + k] = c;
    op[(size_t)t * 2 * Ksz + Ksz + k] = s;
  }
}

extern "C" void kernel_launch(void* const* d_in, const int* in_sizes, int n_in,
                              void* d_out, int out_size, void* d_ws, size_t ws_size,
                              hipStream_t stream) {
  const float* x    = (const float*)d_in[0];
  const float* srr  = (const float*)d_in[1];
  const float* sim  = (const float*)d_in[2];
  const float* traw = (const float*)d_in[3];
  const float* W    = (const float*)d_in[4];
  const float* bias = (const float*)d_in[5];
  float* out = (float*)d_out;

  // ws layout (floats): consts[4096] | U[16777216] | carry[524288] |
  //   prefix[524288] | WfH[65536] | WfL[65536] | partial_v[8192] | wv[256]
  float* wsf    = (float*)d_ws;
  float* consts = wsf;
  float* U      = wsf + 4096;
  float* carry  = U + (size_t)Msz * Ksz;
  float* prefix = carry + (size_t)2 * Bsz * NCH * Ksz;
  unsigned int* WfH = (unsigned int*)(prefix + (size_t)2 * Bsz * NCH * Ksz);
  unsigned int* WfL = WfH + 65536;
  float* partial_v  = (float*)(WfL + 65536);
  float* wv         = partial_v + 16 * Dsz;

  prep1_kernel<<<16, 512, 0, stream>>>(W, partial_v);
  prep2_kernel<<<64, 512, 0, stream>>>(W, partial_v, wv);
  prep3_kernel<<<1, 256, 0, stream>>>(srr, sim, traw, wv, consts);
  wpack_kernel<<<256, 64, 0, stream>>>(W, consts, WfH, WfL);
  gemm_mfma<<<Msz / 64, 256, 0, stream>>>(x, WfH, WfL, bias, consts, U, carry);
  scan_prefix<<<dim3(Bsz, Ksz / 64), 64, 0, stream>>>(consts, carry, prefix);
  scan_final<<<Bsz * NCH, Ksz, 0, stream>>>(U, consts, prefix, out);
}